// Round 1
// baseline (1330.386 us; speedup 1.0000x reference)
//
#include <hip/hip_runtime.h>

// Problem constants (fixed by the reference)
#define BB 16
#define HIS 13
#define NN 400
#define DIN 16
#define HID 256
#define SS 4
#define PRED 12
#define NLAYERS 3
#define NG 1600          // SS*NN
#define NE 9600          // 3*NN*DEG
#define EPSF 1e-5f
#define MTOT (BB*NG)     // 25600
#define HSZ ((size_t)BB*NG*HID)  // 6,553,600 floats

// ---------------------------------------------------------------- degrees
__global__ void k_deg(const int* __restrict__ src, const int* __restrict__ dst,
                      float* __restrict__ outdeg, float* __restrict__ indeg,
                      int* __restrict__ cnt) {
    int e = blockIdx.x * 256 + threadIdx.x;
    if (e < NE) {
        atomicAdd(&outdeg[src[e]], 1.0f);
        atomicAdd(&indeg[dst[e]], 1.0f);
        atomicAdd(&cnt[dst[e]], 1);
    }
}

__global__ void k_inv(float* __restrict__ outdeg, float* __restrict__ indeg) {
    int g = blockIdx.x * 256 + threadIdx.x;
    if (g < NG) {
        outdeg[g] = rsqrtf(fmaxf(outdeg[g], 1.0f));
        indeg[g]  = rsqrtf(fmaxf(indeg[g], 1.0f));
    }
}

// single-block exclusive scan over NG counts
__global__ void k_scan(const int* __restrict__ cnt, int* __restrict__ off) {
    __shared__ int tot[256];
    int t = threadIdx.x;
    const int CH = (NG + 255) / 256; // 7
    int s = 0;
    for (int i = 0; i < CH; ++i) { int g = t * CH + i; if (g < NG) s += cnt[g]; }
    tot[t] = s;
    __syncthreads();
    if (t == 0) {
        int acc = 0;
        for (int i = 0; i < 256; ++i) { int v = tot[i]; tot[i] = acc; acc += v; }
        off[NG] = acc;
    }
    __syncthreads();
    int acc = tot[t];
    for (int i = 0; i < CH; ++i) {
        int g = t * CH + i;
        if (g < NG) { off[g] = acc; acc += cnt[g]; }
    }
}

__global__ void k_fill(const int* __restrict__ src, const int* __restrict__ dst,
                       const float* __restrict__ ew, const float* __restrict__ inv_out,
                       const int* __restrict__ off, int* __restrict__ cursor,
                       int* __restrict__ csr_src, float* __restrict__ csr_coef) {
    int e = blockIdx.x * 256 + threadIdx.x;
    if (e < NE) {
        int d = dst[e];
        int p = off[d] + atomicAdd(&cursor[d], 1);
        int s0 = src[e];
        csr_src[p] = s0;
        csr_coef[p] = ew[e] * inv_out[s0];   // fold inv_out into edge coefficient
    }
}

// ------------------------------------------------------- input projection
// h[b, (t0+ts)*NN+n, :] = inputs[b, time0+ts, n, :] @ W_in + b_in
__global__ void k_inproj(const float* __restrict__ inp, const float* __restrict__ W_in,
                         const float* __restrict__ b_in, float* __restrict__ h,
                         int t0, int time0) {
    int n = blockIdx.x, ts = blockIdx.y, b = blockIdx.z, hid = threadIdx.x;
    int t = t0 + ts, time = time0 + ts;
    __shared__ float xin[DIN];
    if (threadIdx.x < DIN)
        xin[threadIdx.x] = inp[(((size_t)b * HIS + time) * NN + n) * DIN + threadIdx.x];
    __syncthreads();
    float acc = b_in[hid];
#pragma unroll
    for (int d = 0; d < DIN; ++d) acc = fmaf(xin[d], W_in[d * HID + hid], acc);
    h[((size_t)b * NG + (size_t)t * NN + n) * HID + hid] = acc;
}

// copy normalized last slice (t=3) of prev iteration into t=0 slot of h0
__global__ void k_copylast(const float* __restrict__ hprev, float* __restrict__ h0) {
    int n = blockIdx.x, b = blockIdx.y, hid = threadIdx.x;
    h0[((size_t)b * NG + n) * HID + hid] =
        hprev[((size_t)b * NG + 3 * NN + n) * HID + hid];
}

// ---------------------------------------------------------- aggregation
// agg[b,g,:] = inv_in[g] * sum_{j in csr[g]} coef[j] * h[b, src[j], :]
__global__ void k_agg(const float* __restrict__ h, const float* __restrict__ inv_in,
                      const int* __restrict__ off, const int* __restrict__ csr_src,
                      const float* __restrict__ csr_coef, float* __restrict__ agg) {
    int g = blockIdx.x, b = blockIdx.y, hid = threadIdx.x;
    int beg = off[g], end = off[g + 1];
    const float* hb = h + (size_t)b * NG * HID;
    float acc = 0.f;
    for (int j = beg; j < end; ++j) {
        acc = fmaf(csr_coef[j], hb[(size_t)csr_src[j] * HID + hid], acc);
    }
    agg[((size_t)b * NG + g) * HID + hid] = acc * inv_in[g];
}

// ---------------------------------------------------------------- GEMM
// C[M][256] = A[M][256] @ W[256][256] + bias ; MODE 0: relu, MODE 1: +res
template <int MODE>
__global__ __launch_bounds__(256) void k_gemm(const float* __restrict__ A,
                                              const float* __restrict__ W,
                                              const float* __restrict__ bias,
                                              const float* __restrict__ res,
                                              float* __restrict__ C) {
    __shared__ __align__(16) float As[16][68];  // [k][m], pad keeps 16B align
    __shared__ __align__(16) float Bs[16][68];  // [k][n]
    int tid = threadIdx.x;
    int tx = tid & 15, ty = tid >> 4;
    int bm = blockIdx.x * 64, bn = blockIdx.y * 64;
    float acc[4][4] = {};
    for (int k0 = 0; k0 < 256; k0 += 16) {
#pragma unroll
        for (int i = 0; i < 4; ++i) {
            int r = ty + i * 16;
            As[tx][r] = A[(size_t)(bm + r) * 256 + k0 + tx];
        }
#pragma unroll
        for (int i = 0; i < 4; ++i) {
            int k = (tid >> 6) + i * 4;
            int c = tid & 63;
            Bs[k][c] = W[(size_t)(k0 + k) * 256 + bn + c];
        }
        __syncthreads();
#pragma unroll
        for (int kk = 0; kk < 16; ++kk) {
            float4 a  = *(const float4*)&As[kk][ty * 4];
            float4 bv = *(const float4*)&Bs[kk][tx * 4];
            acc[0][0] = fmaf(a.x, bv.x, acc[0][0]);
            acc[0][1] = fmaf(a.x, bv.y, acc[0][1]);
            acc[0][2] = fmaf(a.x, bv.z, acc[0][2]);
            acc[0][3] = fmaf(a.x, bv.w, acc[0][3]);
            acc[1][0] = fmaf(a.y, bv.x, acc[1][0]);
            acc[1][1] = fmaf(a.y, bv.y, acc[1][1]);
            acc[1][2] = fmaf(a.y, bv.z, acc[1][2]);
            acc[1][3] = fmaf(a.y, bv.w, acc[1][3]);
            acc[2][0] = fmaf(a.z, bv.x, acc[2][0]);
            acc[2][1] = fmaf(a.z, bv.y, acc[2][1]);
            acc[2][2] = fmaf(a.z, bv.z, acc[2][2]);
            acc[2][3] = fmaf(a.z, bv.w, acc[2][3]);
            acc[3][0] = fmaf(a.w, bv.x, acc[3][0]);
            acc[3][1] = fmaf(a.w, bv.y, acc[3][1]);
            acc[3][2] = fmaf(a.w, bv.z, acc[3][2]);
            acc[3][3] = fmaf(a.w, bv.w, acc[3][3]);
        }
        __syncthreads();
    }
#pragma unroll
    for (int i = 0; i < 4; ++i) {
        int row = bm + ty * 4 + i;
        int col = bn + tx * 4;
        float4 v;
        v.x = acc[i][0] + bias[col + 0];
        v.y = acc[i][1] + bias[col + 1];
        v.z = acc[i][2] + bias[col + 2];
        v.w = acc[i][3] + bias[col + 3];
        if (MODE == 0) {
            v.x = fmaxf(v.x, 0.f); v.y = fmaxf(v.y, 0.f);
            v.z = fmaxf(v.z, 0.f); v.w = fmaxf(v.w, 0.f);
        } else {
            const float4 r4 = *(const float4*)&res[(size_t)row * 256 + col];
            v.x += r4.x; v.y += r4.y; v.z += r4.z; v.w += r4.w;
        }
        *(float4*)&C[(size_t)row * 256 + col] = v;
    }
}

// ---------------------------------------------------------- global layernorm
__global__ void k_stats(const float* __restrict__ h, float* __restrict__ stats) {
    int tid = threadIdx.x;
    size_t base = (size_t)blockIdx.x * 4096;
    float s = 0.f, s2 = 0.f;
#pragma unroll
    for (int i = 0; i < 4; ++i) {
        float4 v = *(const float4*)(h + base + (size_t)i * 1024 + tid * 4);
        s  += v.x + v.y + v.z + v.w;
        s2 += v.x * v.x + v.y * v.y + v.z * v.z + v.w * v.w;
    }
#pragma unroll
    for (int o = 32; o > 0; o >>= 1) {
        s  += __shfl_down(s,  o, 64);
        s2 += __shfl_down(s2, o, 64);
    }
    __shared__ float ps[4], ps2[4];
    int wid = tid >> 6, lane = tid & 63;
    if (lane == 0) { ps[wid] = s; ps2[wid] = s2; }
    __syncthreads();
    if (tid == 0) {
        atomicAdd(&stats[0], ps[0] + ps[1] + ps[2] + ps[3]);
        atomicAdd(&stats[1], ps2[0] + ps2[1] + ps2[2] + ps2[3]);
    }
}

__global__ void k_norm(float* __restrict__ h, const float* __restrict__ stats) {
    const float inv_m = 1.0f / (float)HSZ;
    float mean = stats[0] * inv_m;
    float var  = stats[1] * inv_m - mean * mean;
    float istd = rsqrtf(var + EPSF);
    size_t i = ((size_t)blockIdx.x * 256 + threadIdx.x) * 4;
    float4 v = *(const float4*)(h + i);
    v.x = (v.x - mean) * istd;
    v.y = (v.y - mean) * istd;
    v.z = (v.z - mean) * istd;
    v.w = (v.w - mean) * istd;
    *(float4*)(h + i) = v;
}

// ---------------------------------------------------------------- head
__global__ void k_head(const float* __restrict__ h, const float* __restrict__ W1,
                       const float* __restrict__ b1, const float* __restrict__ W2,
                       const float* __restrict__ b2, float* __restrict__ out) {
    int n = blockIdx.x, b = blockIdx.y, tid = threadIdx.x;
    float v  = h[((size_t)b * NG + 3 * NN + n) * HID + tid];
    float w2 = W2[tid];
    float b2v = b2[0];
    __shared__ float ps[4];
    for (int p = 0; p < PRED; ++p) {
        float t = fmaxf(fmaf(v, W1[p], b1[p]), 0.f) * w2;
#pragma unroll
        for (int o = 32; o > 0; o >>= 1) t += __shfl_down(t, o, 64);
        int wid = tid >> 6, lane = tid & 63;
        if (lane == 0) ps[wid] = t;
        __syncthreads();
        if (tid == 0) out[(size_t)(b * PRED + p) * NN + n] = ps[0] + ps[1] + ps[2] + ps[3] + b2v;
        __syncthreads();
    }
}

// ---------------------------------------------------------------- launch
extern "C" void kernel_launch(void* const* d_in, const int* in_sizes, int n_in,
                              void* d_out, int out_size, void* d_ws, size_t ws_size,
                              hipStream_t stream) {
    const float* inp   = (const float*)d_in[0];
    const float* W_in  = (const float*)d_in[1];
    const float* b_in  = (const float*)d_in[2];
    const float* gcn_W = (const float*)d_in[3];
    const float* gcn_b = (const float*)d_in[4];
    const float* W1    = (const float*)d_in[5];
    const float* b1    = (const float*)d_in[6];
    const float* W2    = (const float*)d_in[7];
    const float* b2    = (const float*)d_in[8];
    const float* ew    = (const float*)d_in[9];
    const int*   src   = (const int*)d_in[10];
    const int*   dst   = (const int*)d_in[11];
    float* out = (float*)d_out;

    char* w = (char*)d_ws;
    auto alloc = [&](size_t bytes) {
        char* p = w;
        w += (bytes + 255) & ~(size_t)255;
        return p;
    };
    float* h0   = (float*)alloc(HSZ * 4);
    float* hA   = (float*)alloc(HSZ * 4);
    float* hB   = (float*)alloc(HSZ * 4);
    float* agg  = (float*)alloc(HSZ * 4);
    float* inv_out = (float*)alloc(NG * 4);
    float* inv_in  = (float*)alloc(NG * 4);
    int*   csr_off = (int*)alloc((NG + 1) * 4);
    int*   cnt     = (int*)alloc(NG * 4);
    int*   csr_src = (int*)alloc(NE * 4);
    float* csr_coef= (float*)alloc(NE * 4);
    float* stats   = (float*)alloc(8 * 4);

    // ---- graph prep
    hipMemsetAsync(inv_out, 0, NG * 4, stream);
    hipMemsetAsync(inv_in,  0, NG * 4, stream);
    hipMemsetAsync(cnt,     0, NG * 4, stream);
    k_deg<<<(NE + 255) / 256, 256, 0, stream>>>(src, dst, inv_out, inv_in, cnt);
    k_inv<<<(NG + 255) / 256, 256, 0, stream>>>(inv_out, inv_in);
    k_scan<<<1, 256, 0, stream>>>(cnt, csr_off);
    hipMemsetAsync(cnt, 0, NG * 4, stream);
    k_fill<<<(NE + 255) / 256, 256, 0, stream>>>(src, dst, ew, inv_out, csr_off, cnt,
                                                 csr_src, csr_coef);

    // ---- checkpoint loop: rights = {4,7,10,13}
    const int rights[4] = {4, 7, 10, 13};
    int left = 0;
    for (int it = 0; it < 4; ++it) {
        if (it == 0) {
            k_inproj<<<dim3(NN, 4, BB), 256, 0, stream>>>(inp, W_in, b_in, h0, 0, 0);
        } else {
            k_copylast<<<dim3(NN, BB), 256, 0, stream>>>(hA, h0);
            k_inproj<<<dim3(NN, 3, BB), 256, 0, stream>>>(inp, W_in, b_in, h0, 1, left);
        }
        // layer 0: h0 -> hA (relu)
        k_agg<<<dim3(NG, BB), 256, 0, stream>>>(h0, inv_in, csr_off, csr_src, csr_coef, agg);
        k_gemm<0><<<dim3(400, 4), 256, 0, stream>>>(agg, gcn_W + 0 * 65536, gcn_b + 0 * 256,
                                                    nullptr, hA);
        // layer 1: hA -> hB (relu)
        k_agg<<<dim3(NG, BB), 256, 0, stream>>>(hA, inv_in, csr_off, csr_src, csr_coef, agg);
        k_gemm<0><<<dim3(400, 4), 256, 0, stream>>>(agg, gcn_W + 1 * 65536, gcn_b + 1 * 256,
                                                    nullptr, hB);
        // layer 2: hB -> hA (no relu, + residual h0)
        k_agg<<<dim3(NG, BB), 256, 0, stream>>>(hB, inv_in, csr_off, csr_src, csr_coef, agg);
        k_gemm<1><<<dim3(400, 4), 256, 0, stream>>>(agg, gcn_W + 2 * 65536, gcn_b + 2 * 256,
                                                    h0, hA);
        // global layernorm over hA
        hipMemsetAsync(stats, 0, 2 * 4, stream);
        k_stats<<<1600, 256, 0, stream>>>(hA, stats);
        k_norm<<<6400, 256, 0, stream>>>(hA, stats);
        left = rights[it];
    }

    // ---- head
    k_head<<<dim3(NN, BB), 256, 0, stream>>>(hA, W1, b1, W2, b2, out);
}

// Round 2
// 745.070 us; speedup vs baseline: 1.7856x; 1.7856x over previous
//
#include <hip/hip_runtime.h>

// Problem constants (fixed by the reference)
#define BB 16
#define HIS 13
#define NN 400
#define DIN 16
#define HID 256
#define SS 4
#define PRED 12
#define NG 1600          // SS*NN
#define NE 9600          // 3*NN*DEG
#define EPSF 1e-5f
#define HSZ ((size_t)BB*NG*HID)  // 6,553,600 floats

typedef __attribute__((ext_vector_type(8))) short short8v;
typedef __attribute__((ext_vector_type(4))) short short4v;
typedef __attribute__((ext_vector_type(4))) float f32x4;

__device__ __forceinline__ short f2bf(float x) {
    unsigned int u = __float_as_uint(x);
    unsigned int r = (u + 0x7FFF + ((u >> 16) & 1)) >> 16;
    return (short)r;
}

__device__ __forceinline__ void gload16(const void* g, void* l) {
    __builtin_amdgcn_global_load_lds((const __attribute__((address_space(1))) void*)g,
                                     (__attribute__((address_space(3))) void*)l,
                                     16, 0, 0);
}

// ---------------------------------------------------------------- degrees
__global__ void k_deg(const int* __restrict__ src, const int* __restrict__ dst,
                      float* __restrict__ outdeg, float* __restrict__ indeg,
                      int* __restrict__ cnt) {
    int e = blockIdx.x * 256 + threadIdx.x;
    if (e < NE) {
        atomicAdd(&outdeg[src[e]], 1.0f);
        atomicAdd(&indeg[dst[e]], 1.0f);
        atomicAdd(&cnt[dst[e]], 1);
    }
}

__global__ void k_inv(float* __restrict__ outdeg, float* __restrict__ indeg) {
    int g = blockIdx.x * 256 + threadIdx.x;
    if (g < NG) {
        outdeg[g] = rsqrtf(fmaxf(outdeg[g], 1.0f));
        indeg[g]  = rsqrtf(fmaxf(indeg[g], 1.0f));
    }
}

// single-block exclusive scan over NG counts
__global__ void k_scan(const int* __restrict__ cnt, int* __restrict__ off) {
    __shared__ int tot[256];
    int t = threadIdx.x;
    const int CH = (NG + 255) / 256; // 7
    int s = 0;
    for (int i = 0; i < CH; ++i) { int g = t * CH + i; if (g < NG) s += cnt[g]; }
    tot[t] = s;
    __syncthreads();
    if (t == 0) {
        int acc = 0;
        for (int i = 0; i < 256; ++i) { int v = tot[i]; tot[i] = acc; acc += v; }
        off[NG] = acc;
    }
    __syncthreads();
    int acc = tot[t];
    for (int i = 0; i < CH; ++i) {
        int g = t * CH + i;
        if (g < NG) { off[g] = acc; acc += cnt[g]; }
    }
}

__global__ void k_fill(const int* __restrict__ src, const int* __restrict__ dst,
                       const float* __restrict__ ew, const float* __restrict__ inv_out,
                       const int* __restrict__ off, int* __restrict__ cursor,
                       int* __restrict__ csr_src, float* __restrict__ csr_coef) {
    int e = blockIdx.x * 256 + threadIdx.x;
    if (e < NE) {
        int d = dst[e];
        int p = off[d] + atomicAdd(&cursor[d], 1);
        int s0 = src[e];
        csr_src[p] = s0;
        csr_coef[p] = ew[e] * inv_out[s0];   // fold inv_out into edge coefficient
    }
}

// ---------------------------------------------------------- W transpose -> bf16
// Wt[l][n][k] = W[l][k][n]
__global__ void k_wt(const float* __restrict__ W, short* __restrict__ Wt) {
    int l = blockIdx.y, n = blockIdx.x, k = threadIdx.x;
    Wt[((size_t)l * 256 + n) * 256 + k] = f2bf(W[((size_t)l * 256 + k) * 256 + n]);
}

// ------------------------------------------------------- input projection
__global__ void k_inproj(const float* __restrict__ inp, const float* __restrict__ W_in,
                         const float* __restrict__ b_in, float* __restrict__ h,
                         int t0, int time0) {
    int n = blockIdx.x, ts = blockIdx.y, b = blockIdx.z, hid = threadIdx.x;
    int t = t0 + ts, time = time0 + ts;
    __shared__ float xin[DIN];
    if (threadIdx.x < DIN)
        xin[threadIdx.x] = inp[(((size_t)b * HIS + time) * NN + n) * DIN + threadIdx.x];
    __syncthreads();
    float acc = b_in[hid];
#pragma unroll
    for (int d = 0; d < DIN; ++d) acc = fmaf(xin[d], W_in[d * HID + hid], acc);
    h[((size_t)b * NG + (size_t)t * NN + n) * HID + hid] = acc;
}

// copy normalized last slice (t=3) of prev iteration into t=0 slot of h0
__global__ void k_copylast(const float* __restrict__ hprev, float* __restrict__ h0) {
    int n = blockIdx.x, b = blockIdx.y, hid = threadIdx.x;
    h0[((size_t)b * NG + n) * HID + hid] =
        hprev[((size_t)b * NG + 3 * NN + n) * HID + hid];
}

// ---------------------------------------------------------- aggregation (fp32 -> bf16)
// agg[b,g,:] = inv_in[g] * sum_{j in csr[g]} coef[j] * h[b, src[j], :]
__global__ void k_agg(const float* __restrict__ h, const float* __restrict__ inv_in,
                      const int* __restrict__ off, const int* __restrict__ csr_src,
                      const float* __restrict__ csr_coef, short* __restrict__ aggb) {
    int g = blockIdx.x;
    int w = threadIdx.x >> 6, l = threadIdx.x & 63;
    int b = blockIdx.y * 4 + w;
    int beg = off[g], end = off[g + 1];
    const float* hb = h + (size_t)b * NG * HID;
    float4 acc = {0.f, 0.f, 0.f, 0.f};
    for (int j = beg; j < end; ++j) {
        float c = csr_coef[j];
        const float4 v = *(const float4*)&hb[(size_t)csr_src[j] * HID + l * 4];
        acc.x = fmaf(c, v.x, acc.x);
        acc.y = fmaf(c, v.y, acc.y);
        acc.z = fmaf(c, v.z, acc.z);
        acc.w = fmaf(c, v.w, acc.w);
    }
    float s = inv_in[g];
    short4v o;
    o.x = f2bf(acc.x * s); o.y = f2bf(acc.y * s);
    o.z = f2bf(acc.z * s); o.w = f2bf(acc.w * s);
    *(short4v*)&aggb[((size_t)b * NG + g) * HID + l * 4] = o;
}

// ---------------------------------------------------------------- MFMA GEMM
// C[M][256] = bf16(A[M][256]) @ bf16(W[256][256]) + bias ; MODE 0: relu, 1: +res
// A row-major bf16, Bt = W^T row-major bf16 ([n][k]).
template <int MODE>
__global__ __launch_bounds__(256) void k_gemm(const short* __restrict__ A,
                                              const short* __restrict__ Bt,
                                              const float* __restrict__ bias,
                                              const float* __restrict__ res,
                                              float* __restrict__ C) {
    __shared__ short As[64 * 32];     // [row][k]  4KB
    __shared__ short Bs[256 * 32];    // [col][k] 16KB
    int tid = threadIdx.x;
    int wid = tid >> 6, l = tid & 63;
    int l15 = l & 15, l4 = l >> 4;
    int bm = blockIdx.x * 64;
    int wn = wid * 64;
    f32x4 acc[4][4] = {};             // [mi][ni]

    const short* Ag0 = A + (size_t)(bm + (l >> 2)) * 256 + (l & 3) * 8;
    const short* Bg0 = Bt + (size_t)(l >> 2) * 256 + (l & 3) * 8;

    for (int k0 = 0; k0 < 256; k0 += 32) {
        // stage: 20 chunks of 1KB (4 A + 16 B), round-robin over 4 waves
        for (int ch = wid; ch < 20; ch += 4) {
            if (ch < 4)
                gload16(Ag0 + (size_t)ch * 16 * 256 + k0, As + ch * 512);
            else
                gload16(Bg0 + (size_t)(ch - 4) * 16 * 256 + k0, Bs + (ch - 4) * 512);
        }
        __syncthreads();
        short8v a[4], b[4];
#pragma unroll
        for (int mi = 0; mi < 4; ++mi)
            a[mi] = *(const short8v*)&As[(mi * 16 + l15) * 32 + l4 * 8];
#pragma unroll
        for (int ni = 0; ni < 4; ++ni)
            b[ni] = *(const short8v*)&Bs[(wn + ni * 16 + l15) * 32 + l4 * 8];
#pragma unroll
        for (int mi = 0; mi < 4; ++mi)
#pragma unroll
            for (int ni = 0; ni < 4; ++ni)
                acc[mi][ni] = __builtin_amdgcn_mfma_f32_16x16x32_bf16(
                    a[mi], b[ni], acc[mi][ni], 0, 0, 0);
        __syncthreads();
    }
    // epilogue
#pragma unroll
    for (int ni = 0; ni < 4; ++ni) {
        int col = wn + ni * 16 + l15;
        float bv = bias[col];
#pragma unroll
        for (int mi = 0; mi < 4; ++mi) {
            int row0 = bm + mi * 16 + l4 * 4;
#pragma unroll
            for (int r = 0; r < 4; ++r) {
                float v = acc[mi][ni][r] + bv;
                if (MODE == 0) v = fmaxf(v, 0.f);
                else           v += res[(size_t)(row0 + r) * 256 + col];
                C[(size_t)(row0 + r) * 256 + col] = v;
            }
        }
    }
}

// ---------------------------------------------------------- global layernorm
__global__ void k_stats(const float* __restrict__ h, float* __restrict__ stats) {
    int tid = threadIdx.x;
    size_t base = (size_t)blockIdx.x * 4096;
    float s = 0.f, s2 = 0.f;
#pragma unroll
    for (int i = 0; i < 4; ++i) {
        float4 v = *(const float4*)(h + base + (size_t)i * 1024 + tid * 4);
        s  += v.x + v.y + v.z + v.w;
        s2 += v.x * v.x + v.y * v.y + v.z * v.z + v.w * v.w;
    }
#pragma unroll
    for (int o = 32; o > 0; o >>= 1) {
        s  += __shfl_down(s,  o, 64);
        s2 += __shfl_down(s2, o, 64);
    }
    __shared__ float ps[4], ps2[4];
    int wid = tid >> 6, lane = tid & 63;
    if (lane == 0) { ps[wid] = s; ps2[wid] = s2; }
    __syncthreads();
    if (tid == 0) {
        atomicAdd(&stats[0], ps[0] + ps[1] + ps[2] + ps[3]);
        atomicAdd(&stats[1], ps2[0] + ps2[1] + ps2[2] + ps2[3]);
    }
}

__global__ void k_norm(float* __restrict__ h, const float* __restrict__ stats) {
    const float inv_m = 1.0f / (float)HSZ;
    float mean = stats[0] * inv_m;
    float var  = stats[1] * inv_m - mean * mean;
    float istd = rsqrtf(var + EPSF);
    size_t i = ((size_t)blockIdx.x * 256 + threadIdx.x) * 4;
    float4 v = *(const float4*)(h + i);
    v.x = (v.x - mean) * istd;
    v.y = (v.y - mean) * istd;
    v.z = (v.z - mean) * istd;
    v.w = (v.w - mean) * istd;
    *(float4*)(h + i) = v;
}

// ---------------------------------------------------------------- head
__global__ void k_head(const float* __restrict__ h, const float* __restrict__ W1,
                       const float* __restrict__ b1, const float* __restrict__ W2,
                       const float* __restrict__ b2, float* __restrict__ out) {
    int n = blockIdx.x, b = blockIdx.y, tid = threadIdx.x;
    float v  = h[((size_t)b * NG + 3 * NN + n) * HID + tid];
    float w2 = W2[tid];
    float b2v = b2[0];
    __shared__ float ps[4];
    for (int p = 0; p < PRED; ++p) {
        float t = fmaxf(fmaf(v, W1[p], b1[p]), 0.f) * w2;
#pragma unroll
        for (int o = 32; o > 0; o >>= 1) t += __shfl_down(t, o, 64);
        int wid = tid >> 6, lane = tid & 63;
        if (lane == 0) ps[wid] = t;
        __syncthreads();
        if (tid == 0) out[(size_t)(b * PRED + p) * NN + n] = ps[0] + ps[1] + ps[2] + ps[3] + b2v;
        __syncthreads();
    }
}

// ---------------------------------------------------------------- launch
extern "C" void kernel_launch(void* const* d_in, const int* in_sizes, int n_in,
                              void* d_out, int out_size, void* d_ws, size_t ws_size,
                              hipStream_t stream) {
    const float* inp   = (const float*)d_in[0];
    const float* W_in  = (const float*)d_in[1];
    const float* b_in  = (const float*)d_in[2];
    const float* gcn_W = (const float*)d_in[3];
    const float* gcn_b = (const float*)d_in[4];
    const float* W1    = (const float*)d_in[5];
    const float* b1    = (const float*)d_in[6];
    const float* W2    = (const float*)d_in[7];
    const float* b2    = (const float*)d_in[8];
    const float* ew    = (const float*)d_in[9];
    const int*   src   = (const int*)d_in[10];
    const int*   dst   = (const int*)d_in[11];
    float* out = (float*)d_out;

    char* w = (char*)d_ws;
    auto alloc = [&](size_t bytes) {
        char* p = w;
        w += (bytes + 255) & ~(size_t)255;
        return p;
    };
    float* h0   = (float*)alloc(HSZ * 4);
    float* hA   = (float*)alloc(HSZ * 4);
    float* hB   = (float*)alloc(HSZ * 4);
    short* aggb = (short*)alloc(HSZ * 2);
    short* Wt   = (short*)alloc((size_t)3 * 256 * 256 * 2);
    float* inv_out = (float*)alloc(NG * 4);
    float* inv_in  = (float*)alloc(NG * 4);
    int*   csr_off = (int*)alloc((NG + 1) * 4);
    int*   cnt     = (int*)alloc(NG * 4);
    int*   csr_src = (int*)alloc(NE * 4);
    float* csr_coef= (float*)alloc(NE * 4);
    float* stats   = (float*)alloc(8 * 4);

    // ---- graph prep
    hipMemsetAsync(inv_out, 0, NG * 4, stream);
    hipMemsetAsync(inv_in,  0, NG * 4, stream);
    hipMemsetAsync(cnt,     0, NG * 4, stream);
    k_deg<<<(NE + 255) / 256, 256, 0, stream>>>(src, dst, inv_out, inv_in, cnt);
    k_inv<<<(NG + 255) / 256, 256, 0, stream>>>(inv_out, inv_in);
    k_scan<<<1, 256, 0, stream>>>(cnt, csr_off);
    hipMemsetAsync(cnt, 0, NG * 4, stream);
    k_fill<<<(NE + 255) / 256, 256, 0, stream>>>(src, dst, ew, inv_out, csr_off, cnt,
                                                 csr_src, csr_coef);
    k_wt<<<dim3(256, 3), 256, 0, stream>>>(gcn_W, Wt);

    // ---- checkpoint loop: rights = {4,7,10,13}
    const int rights[4] = {4, 7, 10, 13};
    int left = 0;
    for (int it = 0; it < 4; ++it) {
        if (it == 0) {
            k_inproj<<<dim3(NN, 4, BB), 256, 0, stream>>>(inp, W_in, b_in, h0, 0, 0);
        } else {
            k_copylast<<<dim3(NN, BB), 256, 0, stream>>>(hA, h0);
            k_inproj<<<dim3(NN, 3, BB), 256, 0, stream>>>(inp, W_in, b_in, h0, 1, left);
        }
        // layer 0: h0 -> hA (relu)
        k_agg<<<dim3(NG, 4), 256, 0, stream>>>(h0, inv_in, csr_off, csr_src, csr_coef, aggb);
        k_gemm<0><<<dim3(400), 256, 0, stream>>>(aggb, Wt + 0 * 65536, gcn_b + 0 * 256,
                                                 nullptr, hA);
        // layer 1: hA -> hB (relu)
        k_agg<<<dim3(NG, 4), 256, 0, stream>>>(hA, inv_in, csr_off, csr_src, csr_coef, aggb);
        k_gemm<0><<<dim3(400), 256, 0, stream>>>(aggb, Wt + 1 * 65536, gcn_b + 1 * 256,
                                                 nullptr, hB);
        // layer 2: hB -> hA (no relu, + residual h0)
        k_agg<<<dim3(NG, 4), 256, 0, stream>>>(hB, inv_in, csr_off, csr_src, csr_coef, aggb);
        k_gemm<1><<<dim3(400), 256, 0, stream>>>(aggb, Wt + 2 * 65536, gcn_b + 2 * 256,
                                                 h0, hA);
        // global layernorm over hA
        hipMemsetAsync(stats, 0, 2 * 4, stream);
        k_stats<<<1600, 256, 0, stream>>>(hA, stats);
        k_norm<<<6400, 256, 0, stream>>>(hA, stats);
        left = rights[it];
    }

    // ---- head
    k_head<<<dim3(NN, BB), 256, 0, stream>>>(hA, W1, b1, W2, b2, out);
}

// Round 3
// 498.722 us; speedup vs baseline: 2.6676x; 1.4940x over previous
//
#include <hip/hip_runtime.h>

// Problem constants (fixed by the reference)
#define BB 16
#define HIS 13
#define NN 400
#define DIN 16
#define HID 256
#define SS 4
#define PRED 12
#define NG 1600          // SS*NN
#define NE 9600          // 3*NN*DEG
#define EPSF 1e-5f
#define MROWS (BB*NG)                       // 25600 rows, row = g*16 + b
#define HSZ ((size_t)MROWS*HID)             // 6,553,600 elems
#define SLICE_ELEMS ((size_t)NN*BB*HID)     // 1,638,400 elems (t=3 slice)

typedef __attribute__((ext_vector_type(8))) short short8v;
typedef __attribute__((ext_vector_type(4))) float f32x4;

__device__ __forceinline__ short f2bf(float x) {
    unsigned u = __float_as_uint(x);
    return (short)((u + 0x7FFF + ((u >> 16) & 1)) >> 16);
}
__device__ __forceinline__ float bf2f(short x) {
    return __uint_as_float(((unsigned)(unsigned short)x) << 16);
}
__device__ __forceinline__ void gload16(const void* g, void* l) {
    __builtin_amdgcn_global_load_lds((const __attribute__((address_space(1))) void*)g,
                                     (__attribute__((address_space(3))) void*)l,
                                     16, 0, 0);
}

// ---------------------------------------------------------------- degrees
__global__ void k_deg(const int* __restrict__ src, const int* __restrict__ dst,
                      float* __restrict__ outdeg, float* __restrict__ indeg,
                      int* __restrict__ cnt) {
    int e = blockIdx.x * 256 + threadIdx.x;
    if (e < NE) {
        atomicAdd(&outdeg[src[e]], 1.0f);
        atomicAdd(&indeg[dst[e]], 1.0f);
        atomicAdd(&cnt[dst[e]], 1);
    }
}

__global__ void k_inv(float* __restrict__ outdeg, float* __restrict__ indeg) {
    int g = blockIdx.x * 256 + threadIdx.x;
    if (g < NG) {
        outdeg[g] = rsqrtf(fmaxf(outdeg[g], 1.0f));
        indeg[g]  = rsqrtf(fmaxf(indeg[g], 1.0f));
    }
}

// single-block exclusive scan over NG counts
__global__ void k_scan(const int* __restrict__ cnt, int* __restrict__ off) {
    __shared__ int tot[256];
    int t = threadIdx.x;
    const int CH = (NG + 255) / 256; // 7
    int s = 0;
    for (int i = 0; i < CH; ++i) { int g = t * CH + i; if (g < NG) s += cnt[g]; }
    tot[t] = s;
    __syncthreads();
    if (t == 0) {
        int acc = 0;
        for (int i = 0; i < 256; ++i) { int v = tot[i]; tot[i] = acc; acc += v; }
        off[NG] = acc;
    }
    __syncthreads();
    int acc = tot[t];
    for (int i = 0; i < CH; ++i) {
        int g = t * CH + i;
        if (g < NG) { off[g] = acc; acc += cnt[g]; }
    }
}

__global__ void k_fill(const int* __restrict__ src, const int* __restrict__ dst,
                       const float* __restrict__ ew, const float* __restrict__ inv_out,
                       const int* __restrict__ off, int* __restrict__ cursor,
                       int* __restrict__ csr_src, float* __restrict__ csr_coef) {
    int e = blockIdx.x * 256 + threadIdx.x;
    if (e < NE) {
        int d = dst[e];
        int p = off[d] + atomicAdd(&cursor[d], 1);
        int s0 = src[e];
        csr_src[p] = s0;
        csr_coef[p] = ew[e] * inv_out[s0];   // fold inv_out into edge coefficient
    }
}

// ---------------------------------------------------------- W transpose -> bf16
// Wt[l][n][k] = W[l][k][n]
__global__ void k_wt(const float* __restrict__ W, short* __restrict__ Wt) {
    int l = blockIdx.y, n = blockIdx.x, k = threadIdx.x;
    Wt[((size_t)l * 256 + n) * 256 + k] = f2bf(W[((size_t)l * 256 + k) * 256 + n]);
}

// ------------------------------------------------------- input projection
// row g = t*NN+n ; h[(g*16+b)*256 + hid] (bf16, g-major)
__global__ void k_inproj(const float* __restrict__ inp, const float* __restrict__ W_in,
                         const float* __restrict__ b_in, short* __restrict__ h,
                         int t0, int time0) {
    int n = blockIdx.x, ts = blockIdx.y, b = blockIdx.z, hid = threadIdx.x;
    int t = t0 + ts, time = time0 + ts;
    __shared__ float xin[DIN];
    if (threadIdx.x < DIN)
        xin[threadIdx.x] = inp[(((size_t)b * HIS + time) * NN + n) * DIN + threadIdx.x];
    __syncthreads();
    float acc = b_in[hid];
#pragma unroll
    for (int d = 0; d < DIN; ++d) acc = fmaf(xin[d], W_in[d * HID + hid], acc);
    h[(((size_t)t * NN + n) * BB + b) * HID + hid] = f2bf(acc);
}

// normalized copy of t=3 slice (hlast) into t=0 rows of h0 (flat, same order)
__global__ void k_copylast(const short* __restrict__ hlast, const float* __restrict__ st,
                           short* __restrict__ h0) {
    float mean = st[0] * (1.0f / (float)HSZ);
    float var  = st[1] * (1.0f / (float)HSZ) - mean * mean;
    float istd = rsqrtf(var + EPSF);
    size_t i = (size_t)blockIdx.x * 256 + threadIdx.x;
    h0[i] = f2bf((bf2f(hlast[i]) - mean) * istd);
}

// ---------------------------------------------------------- aggregation
// aggb[(g*16+b)*256+:] = inv_in[g] * sum_j coef[j] * h[(src_j*16+b)*256+:]
__global__ void k_agg(const short* __restrict__ h, const float* __restrict__ inv_in,
                      const int* __restrict__ off, const int* __restrict__ csr_src,
                      const float* __restrict__ csr_coef, short* __restrict__ aggb) {
    int g = blockIdx.x;
    int t = threadIdx.x;
    int b = t >> 4;
    int hs = (t & 15) * 16;          // 16 bf16 per thread
    int beg = off[g], end = off[g + 1];
    float acc[16] = {};
    const size_t lane_off = (size_t)b * HID + hs;
    for (int j = beg; j < end; ++j) {
        float c = csr_coef[j];
        size_t base = (size_t)csr_src[j] * BB * HID + lane_off;
        short8v v0 = *(const short8v*)&h[base];
        short8v v1 = *(const short8v*)&h[base + 8];
#pragma unroll
        for (int i = 0; i < 8; ++i) acc[i]     = fmaf(c, bf2f(v0[i]), acc[i]);
#pragma unroll
        for (int i = 0; i < 8; ++i) acc[8 + i] = fmaf(c, bf2f(v1[i]), acc[8 + i]);
    }
    float s = inv_in[g];
    short8v o0, o1;
#pragma unroll
    for (int i = 0; i < 8; ++i) o0[i] = f2bf(acc[i] * s);
#pragma unroll
    for (int i = 0; i < 8; ++i) o1[i] = f2bf(acc[8 + i] * s);
    size_t obase = ((size_t)g * BB + b) * HID + hs;
    *(short8v*)&aggb[obase]     = o0;
    *(short8v*)&aggb[obase + 8] = o1;
}

// ---------------------------------------------------------------- MFMA GEMM
// MODE 0: C(all rows, bf16) = relu(A@W + bias)
// MODE 1: v = A@W + bias + res ; write only rows>=19200 into C (hlast, offset);
//         accumulate global sum/sumsq of v into stats[0..1]
template <int MODE>
__global__ __launch_bounds__(256) void k_gemm(const short* __restrict__ A,
                                              const short* __restrict__ Bt,
                                              const float* __restrict__ bias,
                                              const short* __restrict__ res,
                                              short* __restrict__ C,
                                              float* __restrict__ stats) {
    __shared__ short As[64 * 32];     // [row][k]  4KB
    __shared__ short Bs[256 * 32];    // [col][k] 16KB
    int tid = threadIdx.x;
    int wid = tid >> 6, l = tid & 63;
    int l15 = l & 15, l4 = l >> 4;
    int bm = blockIdx.x * 64;
    int wn = wid * 64;
    f32x4 acc[4][4] = {};             // [mi][ni]

    const short* Ag0 = A + (size_t)(bm + (l >> 2)) * 256 + (l & 3) * 8;
    const short* Bg0 = Bt + (size_t)(l >> 2) * 256 + (l & 3) * 8;

    for (int k0 = 0; k0 < 256; k0 += 32) {
        for (int ch = wid; ch < 20; ch += 4) {
            if (ch < 4)
                gload16(Ag0 + (size_t)ch * 16 * 256 + k0, As + ch * 512);
            else
                gload16(Bg0 + (size_t)(ch - 4) * 16 * 256 + k0, Bs + (ch - 4) * 512);
        }
        __syncthreads();
        short8v a[4], b[4];
#pragma unroll
        for (int mi = 0; mi < 4; ++mi)
            a[mi] = *(const short8v*)&As[(mi * 16 + l15) * 32 + l4 * 8];
#pragma unroll
        for (int ni = 0; ni < 4; ++ni)
            b[ni] = *(const short8v*)&Bs[(wn + ni * 16 + l15) * 32 + l4 * 8];
#pragma unroll
        for (int mi = 0; mi < 4; ++mi)
#pragma unroll
            for (int ni = 0; ni < 4; ++ni)
                acc[mi][ni] = __builtin_amdgcn_mfma_f32_16x16x32_bf16(
                    a[mi], b[ni], acc[mi][ni], 0, 0, 0);
        __syncthreads();
    }
    float s1 = 0.f, s2 = 0.f;
#pragma unroll
    for (int ni = 0; ni < 4; ++ni) {
        int col = wn + ni * 16 + l15;
        float bv = bias[col];
#pragma unroll
        for (int mi = 0; mi < 4; ++mi) {
            int row0 = bm + mi * 16 + l4 * 4;
#pragma unroll
            for (int r = 0; r < 4; ++r) {
                float v = acc[mi][ni][r] + bv;
                if (MODE == 0) {
                    v = fmaxf(v, 0.f);
                    C[(size_t)(row0 + r) * 256 + col] = f2bf(v);
                } else {
                    v += bf2f(res[(size_t)(row0 + r) * 256 + col]);
                    s1 += v;
                    s2 += v * v;
                    if (bm >= 19200)
                        C[(size_t)(row0 + r - 19200) * 256 + col] = f2bf(v);
                }
            }
        }
    }
    if (MODE == 1) {
        __shared__ float red[512];
        red[tid] = s1; red[256 + tid] = s2;
        __syncthreads();
        for (int o = 128; o > 0; o >>= 1) {
            if (tid < o) { red[tid] += red[tid + o]; red[256 + tid] += red[256 + tid + o]; }
            __syncthreads();
        }
        if (tid == 0) {
            atomicAdd(&stats[0], red[0]);
            atomicAdd(&stats[1], red[256]);
        }
    }
}

// ---------------------------------------------------------------- head
__global__ void k_head(const short* __restrict__ hlast, const float* __restrict__ st,
                       const float* __restrict__ W1, const float* __restrict__ b1,
                       const float* __restrict__ W2, const float* __restrict__ b2,
                       float* __restrict__ out) {
    float mean = st[0] * (1.0f / (float)HSZ);
    float var  = st[1] * (1.0f / (float)HSZ) - mean * mean;
    float istd = rsqrtf(var + EPSF);
    int n = blockIdx.x, b = blockIdx.y, tid = threadIdx.x;
    float v  = (bf2f(hlast[((size_t)n * BB + b) * HID + tid]) - mean) * istd;
    float w2 = W2[tid];
    float b2v = b2[0];
    __shared__ float ps[4];
    for (int p = 0; p < PRED; ++p) {
        float t = fmaxf(fmaf(v, W1[p], b1[p]), 0.f) * w2;
#pragma unroll
        for (int o = 32; o > 0; o >>= 1) t += __shfl_down(t, o, 64);
        int wid = tid >> 6, lane = tid & 63;
        if (lane == 0) ps[wid] = t;
        __syncthreads();
        if (tid == 0) out[(size_t)(b * PRED + p) * NN + n] = ps[0] + ps[1] + ps[2] + ps[3] + b2v;
        __syncthreads();
    }
}

// ---------------------------------------------------------------- launch
extern "C" void kernel_launch(void* const* d_in, const int* in_sizes, int n_in,
                              void* d_out, int out_size, void* d_ws, size_t ws_size,
                              hipStream_t stream) {
    const float* inp   = (const float*)d_in[0];
    const float* W_in  = (const float*)d_in[1];
    const float* b_in  = (const float*)d_in[2];
    const float* gcn_W = (const float*)d_in[3];
    const float* gcn_b = (const float*)d_in[4];
    const float* W1    = (const float*)d_in[5];
    const float* b1    = (const float*)d_in[6];
    const float* W2    = (const float*)d_in[7];
    const float* b2    = (const float*)d_in[8];
    const float* ew    = (const float*)d_in[9];
    const int*   src   = (const int*)d_in[10];
    const int*   dst   = (const int*)d_in[11];
    float* out = (float*)d_out;

    char* w = (char*)d_ws;
    auto alloc = [&](size_t bytes) {
        char* p = w;
        w += (bytes + 255) & ~(size_t)255;
        return p;
    };
    short* h0    = (short*)alloc(HSZ * 2);
    short* hA    = (short*)alloc(HSZ * 2);
    short* hB    = (short*)alloc(HSZ * 2);
    short* aggb  = (short*)alloc(HSZ * 2);
    short* hlast = (short*)alloc(SLICE_ELEMS * 2);
    short* Wt    = (short*)alloc((size_t)3 * 256 * 256 * 2);
    float* inv_out = (float*)alloc(NG * 4);
    float* inv_in  = (float*)alloc(NG * 4);
    int*   csr_off = (int*)alloc((NG + 1) * 4);
    int*   cnt     = (int*)alloc(NG * 4);
    int*   csr_src = (int*)alloc(NE * 4);
    float* csr_coef= (float*)alloc(NE * 4);
    float* stats   = (float*)alloc(8 * 4);

    // ---- graph prep
    hipMemsetAsync(inv_out, 0, NG * 4, stream);
    hipMemsetAsync(inv_in,  0, NG * 4, stream);
    hipMemsetAsync(cnt,     0, NG * 4, stream);
    hipMemsetAsync(stats,   0, 8 * 4,  stream);
    k_deg<<<(NE + 255) / 256, 256, 0, stream>>>(src, dst, inv_out, inv_in, cnt);
    k_inv<<<(NG + 255) / 256, 256, 0, stream>>>(inv_out, inv_in);
    k_scan<<<1, 256, 0, stream>>>(cnt, csr_off);
    hipMemsetAsync(cnt, 0, NG * 4, stream);
    k_fill<<<(NE + 255) / 256, 256, 0, stream>>>(src, dst, ew, inv_out, csr_off, cnt,
                                                 csr_src, csr_coef);
    k_wt<<<dim3(256, 3), 256, 0, stream>>>(gcn_W, Wt);

    // ---- checkpoint loop: rights = {4,7,10,13}
    const int rights[4] = {4, 7, 10, 13};
    int left = 0;
    for (int it = 0; it < 4; ++it) {
        if (it == 0) {
            k_inproj<<<dim3(NN, 4, BB), 256, 0, stream>>>(inp, W_in, b_in, h0, 0, 0);
        } else {
            k_copylast<<<6400, 256, 0, stream>>>(hlast, stats + (it - 1) * 2, h0);
            k_inproj<<<dim3(NN, 3, BB), 256, 0, stream>>>(inp, W_in, b_in, h0, 1, left);
        }
        // layer 0: h0 -> hA (relu)
        k_agg<<<NG, 256, 0, stream>>>(h0, inv_in, csr_off, csr_src, csr_coef, aggb);
        k_gemm<0><<<400, 256, 0, stream>>>(aggb, Wt + 0 * 65536, gcn_b + 0 * 256,
                                           nullptr, hA, nullptr);
        // layer 1: hA -> hB (relu)
        k_agg<<<NG, 256, 0, stream>>>(hA, inv_in, csr_off, csr_src, csr_coef, aggb);
        k_gemm<0><<<400, 256, 0, stream>>>(aggb, Wt + 1 * 65536, gcn_b + 1 * 256,
                                           nullptr, hB, nullptr);
        // layer 2: hB -> hlast (t=3 rows only) + stats (sum/sumsq of full h_out)
        k_agg<<<NG, 256, 0, stream>>>(hB, inv_in, csr_off, csr_src, csr_coef, aggb);
        k_gemm<1><<<400, 256, 0, stream>>>(aggb, Wt + 2 * 65536, gcn_b + 2 * 256,
                                           h0, hlast, stats + it * 2);
        left = rights[it];
    }

    // ---- head
    k_head<<<dim3(NN, BB), 256, 0, stream>>>(hlast, stats + 6, W1, b1, W2, b2, out);
}

// Round 4
// 483.849 us; speedup vs baseline: 2.7496x; 1.0307x over previous
//
#include <hip/hip_runtime.h>

// Problem constants (fixed by the reference)
#define BB 16
#define HIS 13
#define NN 400
#define DIN 16
#define HID 256
#define PRED 12
#define NG 1600          // 4*NN
#define NE 9600
#define EPSF 1e-5f
#define MROWS (BB*NG)                       // 25600 rows, row = g*16 + b
#define HSZ ((size_t)MROWS*HID)             // 6,553,600 elems
#define SLICE_ELEMS ((size_t)NN*BB*HID)     // t=3 slice

typedef __attribute__((ext_vector_type(8))) short short8v;
typedef __attribute__((ext_vector_type(4))) float f32x4;

__device__ __forceinline__ short f2bf(float x) {
    unsigned u = __float_as_uint(x);
    return (short)((u + 0x7FFF + ((u >> 16) & 1)) >> 16);
}
__device__ __forceinline__ float bf2f(short x) {
    return __uint_as_float(((unsigned)(unsigned short)x) << 16);
}
__device__ __forceinline__ void gload16(const void* g, void* l) {
    __builtin_amdgcn_global_load_lds((const __attribute__((address_space(1))) void*)g,
                                     (__attribute__((address_space(3))) void*)l,
                                     16, 0, 0);
}

// ------------------------------------------------------------ prep kernel
// block 0           : build CSR (LDS atomics), inv_in, csr_coef, zero stats
// blocks 1..64      : Wt[l][n][k] = bf16(W[l][k][n])
// blocks 65..1664   : input projection for iteration 0 (t = 0..3)
__global__ __launch_bounds__(256) void k_prep(
    const int* __restrict__ src, const int* __restrict__ dst,
    const float* __restrict__ ew, const float* __restrict__ gcn_W,
    const float* __restrict__ inp, const float* __restrict__ W_in,
    const float* __restrict__ b_in,
    float* __restrict__ inv_in, int* __restrict__ csr_off,
    int* __restrict__ csr_src, float* __restrict__ csr_coef,
    short* __restrict__ Wt, short* __restrict__ h0, float* __restrict__ stats)
{
    __shared__ __align__(16) char SM[26624];
    __shared__ int tot[256];
    int t = threadIdx.x, bi = blockIdx.x;
    if (bi == 0) {
        float* odeg = (float*)SM;          // -> inv_out
        float* ideg = odeg + NG;
        int*   cnt  = (int*)(ideg + NG);   // -> cursor
        int*   off  = cnt + NG;            // NG+1
        for (int g = t; g < NG; g += 256) { odeg[g] = 0.f; ideg[g] = 0.f; }
        __syncthreads();
        for (int e = t; e < NE; e += 256) {
            atomicAdd(&odeg[src[e]], 1.f);
            atomicAdd(&ideg[dst[e]], 1.f);
        }
        __syncthreads();
        for (int g = t; g < NG; g += 256) {
            float iv = ideg[g];
            odeg[g] = rsqrtf(fmaxf(odeg[g], 1.f));
            inv_in[g] = rsqrtf(fmaxf(iv, 1.f));
            cnt[g] = (int)iv;
        }
        __syncthreads();
        // exclusive scan cnt -> off
        {
            const int CH = 7;
            int s = 0;
            for (int i = 0; i < CH; ++i) { int g = t * CH + i; if (g < NG) s += cnt[g]; }
            tot[t] = s; __syncthreads();
            if (t == 0) { int a = 0; for (int i = 0; i < 256; ++i) { int v = tot[i]; tot[i] = a; a += v; } off[NG] = a; csr_off[NG] = a; }
            __syncthreads();
            int a = tot[t];
            for (int i = 0; i < CH; ++i) {
                int g = t * CH + i;
                if (g < NG) { off[g] = a; csr_off[g] = a; a += cnt[g]; }
            }
        }
        __syncthreads();
        for (int g = t; g < NG; g += 256) cnt[g] = 0;
        if (t < 8) stats[t] = 0.f;
        __syncthreads();
        for (int e = t; e < NE; e += 256) {
            int d = dst[e];
            int p = off[d] + atomicAdd(&cnt[d], 1);
            int s0 = src[e];
            csr_src[p] = s0;
            csr_coef[p] = ew[e] * odeg[s0];
        }
    } else if (bi <= 64) {
        int base = (bi - 1) * 3072;
#pragma unroll
        for (int k = 0; k < 12; ++k) {
            int i = base + k * 256 + t;               // < 196608
            int l = i >> 16, rem = i & 65535;
            int n = rem >> 8, kk = rem & 255;
            Wt[i] = f2bf(gcn_W[((size_t)(l * 256 + kk)) * 256 + n]);
        }
    } else {
        int job = bi - 65;                 // 0..1599
        int tt = job / NN, n = job % NN;   // t = time = tt
        float* Wl = (float*)SM;            // [16][256]
        float* xs = (float*)(SM + 16384);  // [16][16]
#pragma unroll
        for (int i = 0; i < 16; ++i) Wl[i * 256 + t] = W_in[i * 256 + t];
        { int b = t >> 4, d = t & 15;
          xs[t] = inp[(((size_t)b * HIS + tt) * NN + n) * DIN + d]; }
        __syncthreads();
        float acc[16];
        float bv = b_in[t];
#pragma unroll
        for (int b = 0; b < 16; ++b) acc[b] = bv;
#pragma unroll
        for (int d = 0; d < 16; ++d) {
            float w = Wl[d * 256 + t];
#pragma unroll
            for (int b = 0; b < 16; ++b) acc[b] = fmaf(xs[b * 16 + d], w, acc[b]);
        }
        size_t rowb = ((size_t)tt * NN + n) * BB;
        for (int b = 0; b < 16; ++b) h0[(rowb + b) * HID + t] = f2bf(acc[b]);
    }
}

// ------------------------------------------------------------ input kernel (iters 1..3)
// blocks 0..399   : normalized copy of hlast -> t=0 rows of h0
// blocks 400..1599: input projection t = 1..3, time = left + t - 1
__global__ __launch_bounds__(256) void k_input(
    const float* __restrict__ inp, const float* __restrict__ W_in,
    const float* __restrict__ b_in, const short* __restrict__ hlast,
    const float* __restrict__ st, short* __restrict__ h0, int left)
{
    __shared__ __align__(16) char SM[17408];
    int t = threadIdx.x, bi = blockIdx.x;
    if (bi < 400) {
        float mean = st[0] * (1.f / (float)HSZ);
        float var  = st[1] * (1.f / (float)HSZ) - mean * mean;
        float istd = rsqrtf(var + EPSF);
        size_t base = (size_t)bi * BB * HID;
#pragma unroll
        for (int i = t; i < 512; i += 256) {
            short8v v = *(const short8v*)&hlast[base + (size_t)i * 8];
            short8v o;
#pragma unroll
            for (int j = 0; j < 8; ++j) o[j] = f2bf((bf2f(v[j]) - mean) * istd);
            *(short8v*)&h0[base + (size_t)i * 8] = o;
        }
    } else {
        int job = bi - 400;                   // 0..1199
        int tt = 1 + job / NN, n = job % NN;
        int time = left + tt - 1;
        float* Wl = (float*)SM;
        float* xs = (float*)(SM + 16384);
#pragma unroll
        for (int i = 0; i < 16; ++i) Wl[i * 256 + t] = W_in[i * 256 + t];
        { int b = t >> 4, d = t & 15;
          xs[t] = inp[(((size_t)b * HIS + time) * NN + n) * DIN + d]; }
        __syncthreads();
        float acc[16];
        float bv = b_in[t];
#pragma unroll
        for (int b = 0; b < 16; ++b) acc[b] = bv;
#pragma unroll
        for (int d = 0; d < 16; ++d) {
            float w = Wl[d * 256 + t];
#pragma unroll
            for (int b = 0; b < 16; ++b) acc[b] = fmaf(xs[b * 16 + d], w, acc[b]);
        }
        size_t rowb = ((size_t)tt * NN + n) * BB;
        for (int b = 0; b < 16; ++b) h0[(rowb + b) * HID + t] = f2bf(acc[b]);
    }
}

// ------------------------------------------------------------ fused agg + MFMA GEMM
// Block: 2 g's = 32 rows. Gather agg tile into LDS (fp32 acc -> bf16),
// then C[32][256] = As @ W + bias. MODE 0: relu -> full C. MODE 1: +res,
// stats sum/sumsq, write only rows g>=1200 into hlast.
template <int MODE>
__global__ __launch_bounds__(256) void k_lgemm(
    const short* __restrict__ h, const float* __restrict__ inv_in,
    const int* __restrict__ off, const int* __restrict__ csr_src,
    const float* __restrict__ csr_coef,
    const short* __restrict__ Bt, const float* __restrict__ bias,
    const short* __restrict__ res, short* __restrict__ C,
    float* __restrict__ stats)
{
    __shared__ short As[32][264];     // padded pitch: 528B -> 2-way (free)
    __shared__ short Bs[2][8192];     // [col][32k], source-swizzled
    int tid = threadIdx.x;
    int wid = tid >> 6, l = tid & 63;
    int l15 = l & 15, l4 = l >> 4;
    int g0 = blockIdx.x * 2;
    int bm = g0 * 16;
    int wn = wid * 64;

    // B staging: lane source constants (16B-unit XOR swizzle, m173 pattern)
    int br = l >> 2;
    int kd = (l & 3) ^ ((br >> 1) & 3);
    // prefetch k-chunk 0 during gather
    for (int ch = wid; ch < 16; ch += 4)
        gload16(Bt + ((size_t)(ch * 16 + br)) * 256 + kd * 8, &Bs[0][ch * 512]);

    // ---- gather phase (agg tile -> LDS)
    {
        int b = tid >> 4, hs = (tid & 15) * 16;
        const size_t lane_off = (size_t)b * HID + hs;
        for (int gi = 0; gi < 2; ++gi) {
            int g = g0 + gi;
            int beg = off[g], end = off[g + 1];
            float acc[16];
#pragma unroll
            for (int i = 0; i < 16; ++i) acc[i] = 0.f;
            for (int j = beg; j < end; ++j) {
                float c = csr_coef[j];
                size_t base = (size_t)csr_src[j] * BB * HID + lane_off;
                short8v v0 = *(const short8v*)&h[base];
                short8v v1 = *(const short8v*)&h[base + 8];
#pragma unroll
                for (int i = 0; i < 8; ++i) acc[i]     = fmaf(c, bf2f(v0[i]), acc[i]);
#pragma unroll
                for (int i = 0; i < 8; ++i) acc[8 + i] = fmaf(c, bf2f(v1[i]), acc[8 + i]);
            }
            float s = inv_in[g];
            short8v o0, o1;
#pragma unroll
            for (int i = 0; i < 8; ++i) o0[i] = f2bf(acc[i] * s);
#pragma unroll
            for (int i = 0; i < 8; ++i) o1[i] = f2bf(acc[8 + i] * s);
            int row = gi * 16 + b;
            *(short8v*)&As[row][hs]     = o0;
            *(short8v*)&As[row][hs + 8] = o1;
        }
    }
    __syncthreads();

    f32x4 cacc[2][4] = {};
    int xsw = (l4 ^ ((l15 >> 1) & 3)) * 8;   // swizzled B read offset
    for (int kc = 0; kc < 8; ++kc) {
        int cur = kc & 1;
        if (kc < 7) {
            int k0n = (kc + 1) * 32;
            for (int ch = wid; ch < 16; ch += 4)
                gload16(Bt + ((size_t)(ch * 16 + br)) * 256 + k0n + kd * 8,
                        &Bs[cur ^ 1][ch * 512]);
        }
        int k0 = kc * 32;
        short8v a[2], b[4];
#pragma unroll
        for (int mi = 0; mi < 2; ++mi)
            a[mi] = *(const short8v*)&As[mi * 16 + l15][k0 + l4 * 8];
#pragma unroll
        for (int ni = 0; ni < 4; ++ni)
            b[ni] = *(const short8v*)&Bs[cur][(wn + ni * 16 + l15) * 32 + xsw];
#pragma unroll
        for (int mi = 0; mi < 2; ++mi)
#pragma unroll
            for (int ni = 0; ni < 4; ++ni)
                cacc[mi][ni] = __builtin_amdgcn_mfma_f32_16x16x32_bf16(
                    a[mi], b[ni], cacc[mi][ni], 0, 0, 0);
        __syncthreads();
    }

    float s1 = 0.f, s2 = 0.f;
#pragma unroll
    for (int ni = 0; ni < 4; ++ni) {
        int col = wn + ni * 16 + l15;
        float bv = bias[col];
#pragma unroll
        for (int mi = 0; mi < 2; ++mi) {
            int row0 = bm + mi * 16 + l4 * 4;
#pragma unroll
            for (int r = 0; r < 4; ++r) {
                float v = cacc[mi][ni][r] + bv;
                if (MODE == 0) {
                    v = fmaxf(v, 0.f);
                    C[(size_t)(row0 + r) * HID + col] = f2bf(v);
                } else {
                    v += bf2f(res[(size_t)(row0 + r) * HID + col]);
                    s1 += v; s2 += v * v;
                    if (bm >= 19200)
                        C[(size_t)(row0 + r - 19200) * HID + col] = f2bf(v);
                }
            }
        }
    }
    if (MODE == 1) {
        __shared__ float red[512];
        red[tid] = s1; red[256 + tid] = s2;
        __syncthreads();
        for (int o = 128; o > 0; o >>= 1) {
            if (tid < o) { red[tid] += red[tid + o]; red[256 + tid] += red[256 + tid + o]; }
            __syncthreads();
        }
        if (tid == 0) { atomicAdd(&stats[0], red[0]); atomicAdd(&stats[1], red[256]); }
    }
}

// ---------------------------------------------------------------- head
__global__ void k_head(const short* __restrict__ hlast, const float* __restrict__ st,
                       const float* __restrict__ W1, const float* __restrict__ b1,
                       const float* __restrict__ W2, const float* __restrict__ b2,
                       float* __restrict__ out) {
    float mean = st[0] * (1.0f / (float)HSZ);
    float var  = st[1] * (1.0f / (float)HSZ) - mean * mean;
    float istd = rsqrtf(var + EPSF);
    int n = blockIdx.x, b = blockIdx.y, tid = threadIdx.x;
    float v  = (bf2f(hlast[((size_t)n * BB + b) * HID + tid]) - mean) * istd;
    float w2 = W2[tid];
    float b2v = b2[0];
    __shared__ float ps[4];
    for (int p = 0; p < PRED; ++p) {
        float t = fmaxf(fmaf(v, W1[p], b1[p]), 0.f) * w2;
#pragma unroll
        for (int o = 32; o > 0; o >>= 1) t += __shfl_down(t, o, 64);
        int wid = tid >> 6, lane = tid & 63;
        if (lane == 0) ps[wid] = t;
        __syncthreads();
        if (tid == 0) out[(size_t)(b * PRED + p) * NN + n] = ps[0] + ps[1] + ps[2] + ps[3] + b2v;
        __syncthreads();
    }
}

// ---------------------------------------------------------------- launch
extern "C" void kernel_launch(void* const* d_in, const int* in_sizes, int n_in,
                              void* d_out, int out_size, void* d_ws, size_t ws_size,
                              hipStream_t stream) {
    const float* inp   = (const float*)d_in[0];
    const float* W_in  = (const float*)d_in[1];
    const float* b_in  = (const float*)d_in[2];
    const float* gcn_W = (const float*)d_in[3];
    const float* gcn_b = (const float*)d_in[4];
    const float* W1    = (const float*)d_in[5];
    const float* b1    = (const float*)d_in[6];
    const float* W2    = (const float*)d_in[7];
    const float* b2    = (const float*)d_in[8];
    const float* ew    = (const float*)d_in[9];
    const int*   src   = (const int*)d_in[10];
    const int*   dst   = (const int*)d_in[11];
    float* out = (float*)d_out;

    char* w = (char*)d_ws;
    auto alloc = [&](size_t bytes) {
        char* p = w;
        w += (bytes + 255) & ~(size_t)255;
        return p;
    };
    short* h0    = (short*)alloc(HSZ * 2);
    short* hA    = (short*)alloc(HSZ * 2);
    short* hB    = (short*)alloc(HSZ * 2);
    short* hlast = (short*)alloc(SLICE_ELEMS * 2);
    short* Wt    = (short*)alloc((size_t)3 * 256 * 256 * 2);
    float* inv_in  = (float*)alloc(NG * 4);
    int*   csr_off = (int*)alloc((NG + 1) * 4);
    int*   csr_src = (int*)alloc(NE * 4);
    float* csr_coef= (float*)alloc(NE * 4);
    float* stats   = (float*)alloc(8 * 4);

    k_prep<<<1665, 256, 0, stream>>>(src, dst, ew, gcn_W, inp, W_in, b_in,
                                     inv_in, csr_off, csr_src, csr_coef,
                                     Wt, h0, stats);

    const int rights[4] = {4, 7, 10, 13};
    int left = 0;
    for (int it = 0; it < 4; ++it) {
        if (it > 0)
            k_input<<<1600, 256, 0, stream>>>(inp, W_in, b_in, hlast,
                                              stats + (it - 1) * 2, h0, left);
        k_lgemm<0><<<800, 256, 0, stream>>>(h0, inv_in, csr_off, csr_src, csr_coef,
                                            Wt + 0 * 65536, gcn_b + 0 * 256,
                                            nullptr, hA, nullptr);
        k_lgemm<0><<<800, 256, 0, stream>>>(hA, inv_in, csr_off, csr_src, csr_coef,
                                            Wt + 1 * 65536, gcn_b + 1 * 256,
                                            nullptr, hB, nullptr);
        k_lgemm<1><<<800, 256, 0, stream>>>(hB, inv_in, csr_off, csr_src, csr_coef,
                                            Wt + 2 * 65536, gcn_b + 2 * 256,
                                            h0, hlast, stats + it * 2);
        left = rights[it];
    }

    k_head<<<dim3(NN, BB), 256, 0, stream>>>(hlast, stats + 6, W1, b1, W2, b2, out);
}

// Round 5
// 383.675 us; speedup vs baseline: 3.4675x; 1.2611x over previous
//
#include <hip/hip_runtime.h>

// Problem constants (fixed by the reference)
#define BB 16
#define HIS 13
#define NN 400
#define DIN 16
#define HID 256
#define PRED 12
#define NG 1600
#define NE 9600
#define EPSF 1e-5f
#define HSZ ((size_t)25600*256)             // full h element count (for LN stats)
#define SLICE_ELEMS ((size_t)NN*BB*HID)     // t=3 slice

typedef __attribute__((ext_vector_type(8))) short short8v;
typedef __attribute__((ext_vector_type(4))) float f32x4;

__device__ __forceinline__ short f2bf(float x) {
    unsigned u = __float_as_uint(x);
    return (short)((u + 0x7FFF + ((u >> 16) & 1)) >> 16);
}
__device__ __forceinline__ float bf2f(short x) {
    return __uint_as_float(((unsigned)(unsigned short)x) << 16);
}
__device__ __forceinline__ void gload16(const void* g, void* l) {
    __builtin_amdgcn_global_load_lds((const __attribute__((address_space(1))) void*)g,
                                     (__attribute__((address_space(3))) void*)l,
                                     16, 0, 0);
}

// ------------------------------------------------------------ graph + W prep
// block 0    : degrees over full edge list; X CSR (edges [0,3200), dst in [0,400));
//              Y CSR (edges [6400,9600), dst-1200); inv_in[800]; zero stats
// blocks 1-48: coalesced tile-transpose Wt[l][n][k] = bf16(gcn_W[l][k][n])
__global__ __launch_bounds__(256) void k_graph(
    const int* __restrict__ src, const int* __restrict__ dst,
    const float* __restrict__ ew, const float* __restrict__ gcn_W,
    float* __restrict__ inv_in, int* __restrict__ csr_off,
    int* __restrict__ csr_src, float* __restrict__ csr_coef,
    short* __restrict__ Wt, float* __restrict__ stats)
{
    __shared__ float odeg[NG];
    __shared__ float ideg[NG];
    __shared__ int cnt[400];
    __shared__ int offl[401];
    __shared__ int tot[256];
    __shared__ float S[64][65];
    int t = threadIdx.x, bi = blockIdx.x;
    if (bi == 0) {
        for (int g = t; g < NG; g += 256) { odeg[g] = 0.f; ideg[g] = 0.f; }
        if (t < 8) stats[t] = 0.f;
        __syncthreads();
        for (int e = t; e < NE; e += 256) {
            atomicAdd(&odeg[src[e]], 1.f);
            atomicAdd(&ideg[dst[e]], 1.f);
        }
        __syncthreads();
        for (int g = t; g < 400; g += 256) {
            inv_in[g]       = rsqrtf(fmaxf(ideg[g], 1.f));
            inv_in[400 + g] = rsqrtf(fmaxf(ideg[1200 + g], 1.f));
        }
        // two passes: p=0 -> X graph, p=1 -> Y graph
        for (int p = 0; p < 2; ++p) {
            int ebase = p ? 6400 : 0;
            int doff  = p ? 1200 : 0;
            int cbase = p ? 3200 : 0;
            for (int g = t; g < 400; g += 256) cnt[g] = 0;
            __syncthreads();
            for (int e = t; e < 3200; e += 256)
                atomicAdd(&cnt[dst[ebase + e] - doff], 1);
            __syncthreads();
            // scan 400 counts
            {
                int g0 = t * 2, s = 0;
                if (g0 < 400) s += cnt[g0];
                if (g0 + 1 < 400) s += cnt[g0 + 1];
                tot[t] = s;
                __syncthreads();
                if (t == 0) {
                    int a = 0;
                    for (int i = 0; i < 256; ++i) { int v = tot[i]; tot[i] = a; a += v; }
                    offl[400] = a;
                }
                __syncthreads();
                int a = tot[t];
                if (g0 < 400) { offl[g0] = a; a += cnt[g0]; }
                if (g0 + 1 < 400) offl[g0 + 1] = a;
                __syncthreads();
            }
            for (int g = t; g < 401; g += 256)
                csr_off[(p ? 401 : 0) + g] = cbase + offl[g];
            for (int g = t; g < 400; g += 256) cnt[g] = 0;
            __syncthreads();
            for (int e = t; e < 3200; e += 256) {
                int ee = ebase + e;
                int d = dst[ee] - doff;
                int pp = cbase + offl[d] + atomicAdd(&cnt[d], 1);
                int s0 = src[ee];
                csr_src[pp]  = s0;                                  // absolute row
                csr_coef[pp] = ew[ee] * rsqrtf(fmaxf(odeg[s0], 1.f));
            }
            __syncthreads();
        }
    } else {
        int tile = bi - 1;            // 0..47: 3 layers x 16 (4x4 of 64)
        int l = tile / 16, sub = tile % 16;
        int k0 = (sub >> 2) * 64, n0 = (sub & 3) * 64;
        int tr = t >> 6, tc = t & 63;
#pragma unroll
        for (int i = 0; i < 16; ++i) {
            int r = i * 4 + tr;
            S[r][tc] = gcn_W[(size_t)l * 65536 + (size_t)(k0 + r) * 256 + n0 + tc];
        }
        __syncthreads();
#pragma unroll
        for (int i = 0; i < 16; ++i) {
            int n = i * 4 + tr;
            Wt[(size_t)l * 65536 + (size_t)(n0 + n) * 256 + k0 + tc] = f2bf(S[tc][n]);
        }
    }
}

// ------------------------------------------------------------ input kernel
// 1600 blocks: tt = bi/400, n = bi%400
//  tt=0: FIRST ? inproj(time 0) : normalized copy hlast -> h0 t=0 rows
//  tt=1: inproj -> h0 t=1 rows
//  tt=2: inproj, stats-only contribution (v = gcn_b2 + x), no write
//  tt=3: inproj -> h0 t=3 rows
template <int FIRST>
__global__ __launch_bounds__(256) void k_input(
    const float* __restrict__ inp, const float* __restrict__ W_in,
    const float* __restrict__ b_in, const float* __restrict__ gcn_b2,
    const short* __restrict__ hlast, const float* __restrict__ st,
    short* __restrict__ h0, float* __restrict__ stats_out, int left)
{
    __shared__ float Wl[16 * 256];
    __shared__ float xs[256];
    __shared__ float red[512];
    int t = threadIdx.x, bi = blockIdx.x;
    int tt = bi / 400, n = bi % 400;
    if (!FIRST && tt == 0) {
        float mean = st[0] * (1.f / (float)HSZ);
        float var  = st[1] * (1.f / (float)HSZ) - mean * mean;
        float istd = rsqrtf(var + EPSF);
        size_t base = (size_t)n * BB * HID;
#pragma unroll
        for (int i = t; i < 512; i += 256) {
            short8v v = *(const short8v*)&hlast[base + (size_t)i * 8];
            short8v o;
#pragma unroll
            for (int j = 0; j < 8; ++j) o[j] = f2bf((bf2f(v[j]) - mean) * istd);
            *(short8v*)&h0[base + (size_t)i * 8] = o;
        }
        return;
    }
    int time = FIRST ? tt : (left + tt - 1);
#pragma unroll
    for (int i = 0; i < 16; ++i) Wl[i * 256 + t] = W_in[i * 256 + t];
    { int b = t >> 4, d = t & 15;
      xs[t] = inp[(((size_t)b * HIS + time) * NN + n) * DIN + d]; }
    __syncthreads();
    float acc[16];
    float bv = b_in[t];
#pragma unroll
    for (int b = 0; b < 16; ++b) acc[b] = bv;
#pragma unroll
    for (int d = 0; d < 16; ++d) {
        float w = Wl[d * 256 + t];
#pragma unroll
        for (int b = 0; b < 16; ++b) acc[b] = fmaf(xs[b * 16 + d], w, acc[b]);
    }
    if (tt == 2) {
        float gb = gcn_b2[t];
        float s1 = 0.f, s2 = 0.f;
#pragma unroll
        for (int b = 0; b < 16; ++b) {
            float v = acc[b] + gb;
            s1 += v; s2 += v * v;
        }
        red[t] = s1; red[256 + t] = s2;
        __syncthreads();
        for (int o = 128; o > 0; o >>= 1) {
            if (t < o) { red[t] += red[t + o]; red[256 + t] += red[256 + t + o]; }
            __syncthreads();
        }
        if (t == 0) { atomicAdd(&stats_out[0], red[0]); atomicAdd(&stats_out[1], red[256]); }
    } else {
        size_t rowb = ((size_t)tt * NN + n) * BB;
        for (int b = 0; b < 16; ++b) h0[(rowb + b) * HID + t] = f2bf(acc[b]);
    }
}

// ------------------------------------------------------------ fused agg + MFMA GEMM
// 400 blocks: blk<200 -> X pair (g = 2*blk), else Y pair (g = 1200 + 2*(blk-200)).
// MODE 0: write relu(agg@W+bias) to C rows (absolute). MODE 1: X: stats with
// both residuals (t0,t1 rows); Y: stats + write hlast.
template <int MODE>
__global__ __launch_bounds__(256) void k_layer(
    const short* __restrict__ h, const float* __restrict__ inv_in,
    const int* __restrict__ csr_off, const int* __restrict__ csr_src,
    const float* __restrict__ csr_coef,
    const short* __restrict__ Bt, const float* __restrict__ bias,
    const short* __restrict__ h0res, short* __restrict__ C,
    float* __restrict__ stats)
{
    __shared__ short As[32][264];
    __shared__ short Bs[2][8192];
    __shared__ float red[512];
    int tid = threadIdx.x;
    int wid = tid >> 6, l = tid & 63;
    int l15 = l & 15, l4 = l >> 4;
    int blk = blockIdx.x;
    int isY = blk >= 200;
    int gl0 = (isY ? blk - 200 : blk) * 2;
    int gabs0 = gl0 + (isY ? 1200 : 0);
    int offb = gl0 + (isY ? 401 : 0);
    int invb = gl0 + (isY ? 400 : 0);
    int bm = gabs0 * 16;
    int wn = wid * 64;

    // B staging lane constants (16B-unit XOR source swizzle)
    int br = l >> 2;
    int kd = (l & 3) ^ ((br >> 1) & 3);
    for (int ch = wid; ch < 16; ch += 4)
        gload16(Bt + ((size_t)(ch * 16 + br)) * 256 + kd * 8, &Bs[0][ch * 512]);

    // gather agg tile (2 g's x 16 b = 32 rows) into As
    {
        int b = tid >> 4, hs = (tid & 15) * 16;
        const size_t lane_off = (size_t)b * HID + hs;
        for (int gi = 0; gi < 2; ++gi) {
            int beg = csr_off[offb + gi], end = csr_off[offb + gi + 1];
            float acc[16];
#pragma unroll
            for (int i = 0; i < 16; ++i) acc[i] = 0.f;
            for (int j = beg; j < end; ++j) {
                float c = csr_coef[j];
                size_t base = (size_t)csr_src[j] * BB * HID + lane_off;
                short8v v0 = *(const short8v*)&h[base];
                short8v v1 = *(const short8v*)&h[base + 8];
#pragma unroll
                for (int i = 0; i < 8; ++i) acc[i]     = fmaf(c, bf2f(v0[i]), acc[i]);
#pragma unroll
                for (int i = 0; i < 8; ++i) acc[8 + i] = fmaf(c, bf2f(v1[i]), acc[8 + i]);
            }
            float s = inv_in[invb + gi];
            short8v o0, o1;
#pragma unroll
            for (int i = 0; i < 8; ++i) o0[i] = f2bf(acc[i] * s);
#pragma unroll
            for (int i = 0; i < 8; ++i) o1[i] = f2bf(acc[8 + i] * s);
            int row = gi * 16 + b;
            *(short8v*)&As[row][hs]     = o0;
            *(short8v*)&As[row][hs + 8] = o1;
        }
    }
    __syncthreads();

    f32x4 cacc[2][4] = {};
    int xsw = (l4 ^ ((l15 >> 1) & 3)) * 8;
    for (int kc = 0; kc < 8; ++kc) {
        int cur = kc & 1;
        if (kc < 7) {
            int k0n = (kc + 1) * 32;
            for (int ch = wid; ch < 16; ch += 4)
                gload16(Bt + ((size_t)(ch * 16 + br)) * 256 + k0n + kd * 8,
                        &Bs[cur ^ 1][ch * 512]);
        }
        int k0 = kc * 32;
        short8v a[2], b[4];
#pragma unroll
        for (int mi = 0; mi < 2; ++mi)
            a[mi] = *(const short8v*)&As[mi * 16 + l15][k0 + l4 * 8];
#pragma unroll
        for (int ni = 0; ni < 4; ++ni)
            b[ni] = *(const short8v*)&Bs[cur][(wn + ni * 16 + l15) * 32 + xsw];
#pragma unroll
        for (int mi = 0; mi < 2; ++mi)
#pragma unroll
            for (int ni = 0; ni < 4; ++ni)
                cacc[mi][ni] = __builtin_amdgcn_mfma_f32_16x16x32_bf16(
                    a[mi], b[ni], cacc[mi][ni], 0, 0, 0);
        __syncthreads();
    }

    float s1 = 0.f, s2 = 0.f;
#pragma unroll
    for (int ni = 0; ni < 4; ++ni) {
        int col = wn + ni * 16 + l15;
        float bv = bias[col];
#pragma unroll
        for (int mi = 0; mi < 2; ++mi) {
            int row0 = bm + mi * 16 + l4 * 4;
#pragma unroll
            for (int r = 0; r < 4; ++r) {
                float base = cacc[mi][ni][r] + bv;
                int row = row0 + r;
                if (MODE == 0) {
                    C[(size_t)row * HID + col] = f2bf(fmaxf(base, 0.f));
                } else {
                    if (!isY) {
                        float v1 = base + bf2f(h0res[(size_t)row * HID + col]);
                        float v2 = base + bf2f(h0res[(size_t)(row + 6400) * HID + col]);
                        s1 += v1 + v2; s2 += v1 * v1 + v2 * v2;
                    } else {
                        float v = base + bf2f(h0res[(size_t)row * HID + col]);
                        s1 += v; s2 += v * v;
                        C[(size_t)(row - 19200) * HID + col] = f2bf(v);
                    }
                }
            }
        }
    }
    if (MODE == 1) {
        red[tid] = s1; red[256 + tid] = s2;
        __syncthreads();
        for (int o = 128; o > 0; o >>= 1) {
            if (tid < o) { red[tid] += red[tid + o]; red[256 + tid] += red[256 + tid + o]; }
            __syncthreads();
        }
        if (tid == 0) { atomicAdd(&stats[0], red[0]); atomicAdd(&stats[1], red[256]); }
    }
}

// ---------------------------------------------------------------- head
__global__ void k_head(const short* __restrict__ hlast, const float* __restrict__ st,
                       const float* __restrict__ W1, const float* __restrict__ b1,
                       const float* __restrict__ W2, const float* __restrict__ b2,
                       float* __restrict__ out) {
    float mean = st[0] * (1.0f / (float)HSZ);
    float var  = st[1] * (1.0f / (float)HSZ) - mean * mean;
    float istd = rsqrtf(var + EPSF);
    int n = blockIdx.x, b = blockIdx.y, tid = threadIdx.x;
    float v  = (bf2f(hlast[((size_t)n * BB + b) * HID + tid]) - mean) * istd;
    float w2 = W2[tid];
    float b2v = b2[0];
    __shared__ float ps[4];
    for (int p = 0; p < PRED; ++p) {
        float t = fmaxf(fmaf(v, W1[p], b1[p]), 0.f) * w2;
#pragma unroll
        for (int o = 32; o > 0; o >>= 1) t += __shfl_down(t, o, 64);
        int wid = tid >> 6, lane = tid & 63;
        if (lane == 0) ps[wid] = t;
        __syncthreads();
        if (tid == 0) out[(size_t)(b * PRED + p) * NN + n] = ps[0] + ps[1] + ps[2] + ps[3] + b2v;
        __syncthreads();
    }
}

// ---------------------------------------------------------------- launch
extern "C" void kernel_launch(void* const* d_in, const int* in_sizes, int n_in,
                              void* d_out, int out_size, void* d_ws, size_t ws_size,
                              hipStream_t stream) {
    const float* inp   = (const float*)d_in[0];
    const float* W_in  = (const float*)d_in[1];
    const float* b_in  = (const float*)d_in[2];
    const float* gcn_W = (const float*)d_in[3];
    const float* gcn_b = (const float*)d_in[4];
    const float* W1    = (const float*)d_in[5];
    const float* b1    = (const float*)d_in[6];
    const float* W2    = (const float*)d_in[7];
    const float* b2    = (const float*)d_in[8];
    const float* ew    = (const float*)d_in[9];
    const int*   src   = (const int*)d_in[10];
    const int*   dst   = (const int*)d_in[11];
    float* out = (float*)d_out;

    char* w = (char*)d_ws;
    auto alloc = [&](size_t bytes) {
        char* p = w;
        w += (bytes + 255) & ~(size_t)255;
        return p;
    };
    short* h0    = (short*)alloc(HSZ * 2);
    short* hA    = (short*)alloc(HSZ * 2);
    short* hB    = (short*)alloc(HSZ * 2);
    short* hlast = (short*)alloc(SLICE_ELEMS * 2);
    short* Wt    = (short*)alloc((size_t)3 * 256 * 256 * 2);
    float* inv_in  = (float*)alloc(800 * 4);
    int*   csr_off = (int*)alloc(802 * 4);
    int*   csr_src = (int*)alloc(6400 * 4);
    float* csr_coef= (float*)alloc(6400 * 4);
    float* stats   = (float*)alloc(8 * 4);

    k_graph<<<49, 256, 0, stream>>>(src, dst, ew, gcn_W, inv_in, csr_off,
                                    csr_src, csr_coef, Wt, stats);

    const int lefts[4] = {0, 4, 7, 10};
    for (int it = 0; it < 4; ++it) {
        if (it == 0)
            k_input<1><<<1600, 256, 0, stream>>>(inp, W_in, b_in, gcn_b + 512,
                                                 hlast, stats, h0, stats, 0);
        else
            k_input<0><<<1600, 256, 0, stream>>>(inp, W_in, b_in, gcn_b + 512,
                                                 hlast, stats + (it - 1) * 2, h0,
                                                 stats + it * 2, lefts[it]);
        k_layer<0><<<400, 256, 0, stream>>>(h0, inv_in, csr_off, csr_src, csr_coef,
                                            Wt + 0 * 65536, gcn_b + 0 * 256,
                                            nullptr, hA, nullptr);
        k_layer<0><<<400, 256, 0, stream>>>(hA, inv_in, csr_off, csr_src, csr_coef,
                                            Wt + 1 * 65536, gcn_b + 1 * 256,
                                            nullptr, hB, nullptr);
        k_layer<1><<<400, 256, 0, stream>>>(hB, inv_in, csr_off, csr_src, csr_coef,
                                            Wt + 2 * 65536, gcn_b + 2 * 256,
                                            h0, hlast, stats + it * 2);
    }

    k_head<<<dim3(NN, BB), 256, 0, stream>>>(hlast, stats + 6, W1, b1, W2, b2, out);
}

// Round 6
// 327.503 us; speedup vs baseline: 4.0622x; 1.1715x over previous
//
#include <hip/hip_runtime.h>

// Problem constants (fixed by the reference)
#define BB 16
#define HIS 13
#define NN 400
#define DIN 16
#define HID 256
#define PRED 12
#define NE 9600
#define EPSF 1e-5f
#define HSZ ((size_t)25600*256)            // full h element count (LN stats denom)
#define BAND ((size_t)NN*BB*HID)           // 1,638,400 elems (one t-band)
#define ROWS_BAND (NN*BB)                  // 6400 rows per band
#define CSR_CAP 4608

typedef __attribute__((ext_vector_type(8))) short short8v;
typedef __attribute__((ext_vector_type(4))) float f32x4;

__device__ __forceinline__ short f2bf(float x) {
    unsigned u = __float_as_uint(x);
    return (short)((u + 0x7FFF + ((u >> 16) & 1)) >> 16);
}
__device__ __forceinline__ float bf2f(short x) {
    return __uint_as_float(((unsigned)(unsigned short)x) << 16);
}
__device__ __forceinline__ void gload16(const void* g, void* l) {
    __builtin_amdgcn_global_load_lds((const __attribute__((address_space(1))) void*)g,
                                     (__attribute__((address_space(3))) void*)l,
                                     16, 0, 0);
}

// ------------------------------------------------------------ graph + W prep
// block 0    : degrees; single padded X CSR (dst in [0,400)); cf1 (X), cf2 (Y),
//              csum, inv_in; stats zero + identity slot.
// blocks 1-48: coalesced tile-transpose Wt[l][n][k] = bf16(gcn_W[l][k][n])
__global__ __launch_bounds__(256) void k_graph(
    const int* __restrict__ src, const int* __restrict__ dst,
    const float* __restrict__ ew, const float* __restrict__ gcn_W,
    float* __restrict__ inv_in, float* __restrict__ csum,
    int* __restrict__ csr_off, int* __restrict__ csr_src,
    float* __restrict__ cf1, float* __restrict__ cf2,
    short* __restrict__ Wt, float* __restrict__ stats)
{
    __shared__ int odeg[1600];
    __shared__ int ideg[400];
    __shared__ int cnt[400];
    __shared__ int offl[401];
    __shared__ int scan_t[256];
    __shared__ float csuml[400];
    __shared__ float S[64][65];
    int t = threadIdx.x, bi = blockIdx.x;
    if (bi == 0) {
        for (int g = t; g < 1600; g += 256) odeg[g] = 0;
        for (int g = t; g < 400; g += 256) { ideg[g] = 0; cnt[g] = 0; csuml[g] = 0.f; }
        if (t < 9) stats[t] = 0.f;
        if (t == 9) stats[9] = (1.0f - EPSF) * (float)HSZ;   // identity affine slot
        __syncthreads();
        for (int e = t; e < NE; e += 256) atomicAdd(&odeg[src[e]], 1);
        for (int e = t; e < 3200; e += 256) atomicAdd(&ideg[dst[e]], 1);
        __syncthreads();
        // padded counts (+3 & ~3) + parallel exclusive scan over 400
        int s = 0, p0 = 0, p1 = 0;
        if (t < 200) {
            p0 = (ideg[2 * t] + 3) & ~3;
            p1 = (ideg[2 * t + 1] + 3) & ~3;
            s = p0 + p1;
        }
        scan_t[t] = s;
        __syncthreads();
        for (int o = 1; o < 256; o <<= 1) {
            int v = (t >= o) ? scan_t[t - o] : 0;
            __syncthreads();
            scan_t[t] += v;
            __syncthreads();
        }
        if (t < 200) { int base = scan_t[t] - s; offl[2 * t] = base; offl[2 * t + 1] = base + p0; }
        if (t == 255) offl[400] = scan_t[255];
        __syncthreads();
        int cap = offl[400];
        for (int g = t; g < 401; g += 256) csr_off[g] = offl[g];
        for (int g = t; g < 400; g += 256) inv_in[g] = rsqrtf(fmaxf((float)ideg[g], 1.f));
        for (int i = t; i < cap; i += 256) { csr_src[i] = 0; cf1[i] = 0.f; cf2[i] = 0.f; }
        __syncthreads();
        for (int e = t; e < 3200; e += 256) {
            int d = dst[e];                 // [0,400)
            int r = src[e];                 // [0,400)
            int p = offl[d] + atomicAdd(&cnt[d], 1);
            float w = ew[e];
            float c1 = w * rsqrtf(fmaxf((float)odeg[r], 1.f));
            float c2 = w * rsqrtf(fmaxf((float)odeg[1200 + r], 1.f));
            csr_src[p] = r;
            cf1[p] = c1;
            cf2[p] = c2;
            atomicAdd(&csuml[d], c1);
        }
        __syncthreads();
        for (int g = t; g < 400; g += 256) csum[g] = csuml[g];
    } else {
        int tile = bi - 1;            // 0..47: 3 layers x 16 (4x4 of 64)
        int l = tile / 16, sub = tile % 16;
        int k0 = (sub >> 2) * 64, n0 = (sub & 3) * 64;
        int tr = t >> 6, tc = t & 63;
#pragma unroll
        for (int i = 0; i < 16; ++i) {
            int r = i * 4 + tr;
            S[r][tc] = gcn_W[(size_t)l * 65536 + (size_t)(k0 + r) * 256 + n0 + tc];
        }
        __syncthreads();
#pragma unroll
        for (int i = 0; i < 16; ++i) {
            int n = i * 4 + tr;
            Wt[(size_t)l * 65536 + (size_t)(n0 + n) * 256 + k0 + tc] = f2bf(S[tc][n]);
        }
    }
}

// ------------------------------------------------------------ all input projections
// 5200 blocks: time = bi/400 in [0,13), n = bi%400.
// stat times {2,5,8,11}: add sum/sumsq of (proj + gcn_b2) to stats[it*2], no store.
// other times: store bf16 band xproj[time][n][b][hid] (coalesced via LDS).
__global__ __launch_bounds__(256) void k_xproj(
    const float* __restrict__ inp, const float* __restrict__ W_in,
    const float* __restrict__ b_in, const float* __restrict__ gb2,
    short* __restrict__ xproj, float* __restrict__ stats)
{
    __shared__ float Wl[16 * 256];
    __shared__ float xs[256];
    __shared__ short stg[16 * 256];
    __shared__ float red[512];
    int t = threadIdx.x, bi = blockIdx.x;
    int time = bi / 400, n = bi % 400;
#pragma unroll
    for (int i = 0; i < 16; ++i) Wl[i * 256 + t] = W_in[i * 256 + t];
    { int b = t >> 4, d = t & 15;
      xs[t] = inp[(((size_t)b * HIS + time) * NN + n) * DIN + d]; }
    __syncthreads();
    float acc[16];
    float bv = b_in[t];
#pragma unroll
    for (int b = 0; b < 16; ++b) acc[b] = bv;
#pragma unroll
    for (int d = 0; d < 16; ++d) {
        float w = Wl[d * 256 + t];
#pragma unroll
        for (int b = 0; b < 16; ++b) acc[b] = fmaf(xs[b * 16 + d], w, acc[b]);
    }
    bool isStat = (time == 2 || time == 5 || time == 8 || time == 11);
    if (isStat) {
        float gb = gb2[t];
        float s1 = 0.f, s2 = 0.f;
#pragma unroll
        for (int b = 0; b < 16; ++b) {
            float v = acc[b] + gb;
            s1 += v; s2 += v * v;
        }
        red[t] = s1; red[256 + t] = s2;
        __syncthreads();
        for (int o = 128; o > 0; o >>= 1) {
            if (t < o) { red[t] += red[t + o]; red[256 + t] += red[256 + t + o]; }
            __syncthreads();
        }
        if (t == 0) {
            int it = (time - 2) / 3;
            atomicAdd(&stats[it * 2], red[0]);
            atomicAdd(&stats[it * 2 + 1], red[256]);
        }
    } else {
#pragma unroll
        for (int b = 0; b < 16; ++b) stg[b * 256 + t] = f2bf(acc[b]);
        __syncthreads();
        int b = t >> 4, c = (t & 15) * 16;
        size_t gbase = (size_t)time * BAND + ((size_t)n * 16 + b) * HID + c;
        *(short8v*)&xproj[gbase]     = *(short8v*)&stg[b * 256 + c];
        *(short8v*)&xproj[gbase + 8] = *(short8v*)&stg[b * 256 + c + 8];
    }
}

// ------------------------------------------------------------ fused agg + MFMA GEMM
// 200 blocks: blk<100 -> X (gl = blk*4), else Y (gl = (blk-100)*4). Local rows
// [0,6400) per band; C compact = [X band | Y band].
// MODE 0: gather hX with affine(stA)+csum (X) / hY raw (Y); relu -> C.
// MODE 1: gather compact h; relu -> C.
// MODE 2: gather compact h; epilogue: X: stats with residuals affine(resX0)+resX1;
//         Y: stats + resY, write hlast band (C).
template <int MODE>
__global__ __launch_bounds__(256) void k_layer(
    const short* __restrict__ hX, const short* __restrict__ hY,
    const float* __restrict__ stA, const float* __restrict__ csum,
    const float* __restrict__ inv_in, const int* __restrict__ csr_off,
    const int* __restrict__ csr_src, const float* __restrict__ cf1,
    const float* __restrict__ cf2,
    const short* __restrict__ Bt, const float* __restrict__ bias,
    const short* __restrict__ resX0, const float* __restrict__ stR,
    const short* __restrict__ resX1, const short* __restrict__ resY,
    short* __restrict__ C, float* __restrict__ stats)
{
    __shared__ short As[64][264];
    __shared__ short Bs[2][8192];
    __shared__ float red[512];
    int tid = threadIdx.x;
    int wid = tid >> 6, l = tid & 63;
    int l15 = l & 15, l4 = l >> 4;
    int blk = blockIdx.x;
    int isY = blk >= 100;
    int gl = (isY ? blk - 100 : blk) * 4;
    int rowL0 = gl * 16;
    int wn = wid * 64;
    const short* hsrc = isY ? hY : hX;
    const float* cf = isY ? cf2 : cf1;

    // affine for MODE0 X gather
    float am = 1.f, moff = 0.f;
    if (MODE == 0 && !isY) {
        float mean = stA[0] * (1.f / (float)HSZ);
        float var  = stA[1] * (1.f / (float)HSZ) - mean * mean;
        float istd = rsqrtf(var + EPSF);
        am = istd; moff = mean * istd;
    }

    // B staging lane constants (16B-unit XOR source swizzle) + chunk-0 prefetch
    int br = l >> 2;
    int kd = (l & 3) ^ ((br >> 1) & 3);
    for (int ch = wid; ch < 16; ch += 4)
        gload16(Bt + ((size_t)(ch * 16 + br)) * 256 + kd * 8, &Bs[0][ch * 512]);

    // ---- gather: 4 g's, padded 4-edge chunks
    {
        int b = tid >> 4, hsc = (tid & 15) * 16;
        const size_t lane_off = (size_t)b * HID + hsc;
        for (int gi = 0; gi < 4; ++gi) {
            int g = gl + gi;
            int beg = csr_off[g], end = csr_off[g + 1];
            float acc[16];
#pragma unroll
            for (int i = 0; i < 16; ++i) acc[i] = 0.f;
            for (int j = beg; j < end; j += 4) {
                int ss[4]; float cc[4];
#pragma unroll
                for (int u = 0; u < 4; ++u) { ss[u] = csr_src[j + u]; cc[u] = cf[j + u]; }
                short8v va[4], vb[4];
#pragma unroll
                for (int u = 0; u < 4; ++u) {
                    const short8v* q = (const short8v*)&hsrc[(size_t)ss[u] * 4096 + lane_off];
                    va[u] = q[0]; vb[u] = q[1];
                }
#pragma unroll
                for (int u = 0; u < 4; ++u) {
#pragma unroll
                    for (int i = 0; i < 8; ++i) {
                        acc[i]     = fmaf(cc[u], bf2f(va[u][i]), acc[i]);
                        acc[8 + i] = fmaf(cc[u], bf2f(vb[u][i]), acc[8 + i]);
                    }
                }
            }
            float s = inv_in[g];
            float addv = (MODE == 0 && !isY) ? (-moff * csum[g]) : 0.f;
            short8v o0, o1;
#pragma unroll
            for (int i = 0; i < 8; ++i) o0[i] = f2bf(s * fmaf(am, acc[i], addv));
#pragma unroll
            for (int i = 0; i < 8; ++i) o1[i] = f2bf(s * fmaf(am, acc[8 + i], addv));
            int row = gi * 16 + b;
            *(short8v*)&As[row][hsc]     = o0;
            *(short8v*)&As[row][hsc + 8] = o1;
        }
    }
    __syncthreads();

    // ---- MFMA loop
    f32x4 cacc[4][4] = {};
    int xsw = (l4 ^ ((l15 >> 1) & 3)) * 8;
    for (int kc = 0; kc < 8; ++kc) {
        int cur = kc & 1;
        if (kc < 7) {
            int k0n = (kc + 1) * 32;
            for (int ch = wid; ch < 16; ch += 4)
                gload16(Bt + ((size_t)(ch * 16 + br)) * 256 + k0n + kd * 8,
                        &Bs[cur ^ 1][ch * 512]);
        }
        int k0 = kc * 32;
        short8v av[4], bv[4];
#pragma unroll
        for (int mi = 0; mi < 4; ++mi)
            av[mi] = *(const short8v*)&As[mi * 16 + l15][k0 + l4 * 8];
#pragma unroll
        for (int ni = 0; ni < 4; ++ni)
            bv[ni] = *(const short8v*)&Bs[cur][(wn + ni * 16 + l15) * 32 + xsw];
#pragma unroll
        for (int mi = 0; mi < 4; ++mi)
#pragma unroll
            for (int ni = 0; ni < 4; ++ni)
                cacc[mi][ni] = __builtin_amdgcn_mfma_f32_16x16x32_bf16(
                    av[mi], bv[ni], cacc[mi][ni], 0, 0, 0);
        __syncthreads();
    }

    // ---- epilogue
    if (MODE <= 1) {
        // relu(base+bias) -> LDS stage -> coalesced stores
#pragma unroll
        for (int ni = 0; ni < 4; ++ni) {
            int col = wn + ni * 16 + l15;
            float bvv = bias[col];
#pragma unroll
            for (int mi = 0; mi < 4; ++mi) {
#pragma unroll
                for (int r = 0; r < 4; ++r) {
                    float v = fmaxf(cacc[mi][ni][r] + bvv, 0.f);
                    As[mi * 16 + l4 * 4 + r][col] = f2bf(v);
                }
            }
        }
        __syncthreads();
        int row = tid >> 2, cs = (tid & 3) * 64;
        size_t gb = ((size_t)(isY ? ROWS_BAND : 0) + rowL0 + row) * HID + cs;
#pragma unroll
        for (int i = 0; i < 8; ++i)
            *(short8v*)&C[gb + i * 8] = *(const short8v*)&As[row][cs + i * 8];
    } else {
        float s1 = 0.f, s2 = 0.f;
        if (!isY) {
            float meanR = stR[0] * (1.f / (float)HSZ);
            float varR  = stR[1] * (1.f / (float)HSZ) - meanR * meanR;
            float istdR = rsqrtf(varR + EPSF);
#pragma unroll
            for (int ni = 0; ni < 4; ++ni) {
                int col = wn + ni * 16 + l15;
                float bvv = bias[col];
#pragma unroll
                for (int mi = 0; mi < 4; ++mi) {
#pragma unroll
                    for (int r = 0; r < 4; ++r) {
                        int rowg = rowL0 + mi * 16 + l4 * 4 + r;
                        size_t ix = (size_t)rowg * HID + col;
                        float base = cacc[mi][ni][r] + bvv;
                        float v1 = base + (bf2f(resX0[ix]) - meanR) * istdR;
                        float v2 = base + bf2f(resX1[ix]);
                        s1 += v1 + v2;
                        s2 += v1 * v1 + v2 * v2;
                    }
                }
            }
        } else {
#pragma unroll
            for (int ni = 0; ni < 4; ++ni) {
                int col = wn + ni * 16 + l15;
                float bvv = bias[col];
#pragma unroll
                for (int mi = 0; mi < 4; ++mi) {
#pragma unroll
                    for (int r = 0; r < 4; ++r) {
                        int rowl = mi * 16 + l4 * 4 + r;
                        size_t ix = (size_t)(rowL0 + rowl) * HID + col;
                        float v = cacc[mi][ni][r] + bvv + bf2f(resY[ix]);
                        s1 += v; s2 += v * v;
                        As[rowl][col] = f2bf(v);
                    }
                }
            }
            __syncthreads();
            int row = tid >> 2, cs = (tid & 3) * 64;
            size_t gb = (size_t)(rowL0 + row) * HID + cs;
#pragma unroll
            for (int i = 0; i < 8; ++i)
                *(short8v*)&C[gb + i * 8] = *(const short8v*)&As[row][cs + i * 8];
        }
        red[tid] = s1; red[256 + tid] = s2;
        __syncthreads();
        for (int o = 128; o > 0; o >>= 1) {
            if (tid < o) { red[tid] += red[tid + o]; red[256 + tid] += red[256 + tid + o]; }
            __syncthreads();
        }
        if (tid == 0) { atomicAdd(&stats[0], red[0]); atomicAdd(&stats[1], red[256]); }
    }
}

// ---------------------------------------------------------------- head
__global__ void k_head(const short* __restrict__ hlast, const float* __restrict__ st,
                       const float* __restrict__ W1, const float* __restrict__ b1,
                       const float* __restrict__ W2, const float* __restrict__ b2,
                       float* __restrict__ out) {
    float mean = st[0] * (1.0f / (float)HSZ);
    float var  = st[1] * (1.0f / (float)HSZ) - mean * mean;
    float istd = rsqrtf(var + EPSF);
    int n = blockIdx.x, b = blockIdx.y, tid = threadIdx.x;
    float v  = (bf2f(hlast[((size_t)n * BB + b) * HID + tid]) - mean) * istd;
    float w2 = W2[tid];
    float b2v = b2[0];
    __shared__ float ps[4];
    for (int p = 0; p < PRED; ++p) {
        float t = fmaxf(fmaf(v, W1[p], b1[p]), 0.f) * w2;
#pragma unroll
        for (int o = 32; o > 0; o >>= 1) t += __shfl_down(t, o, 64);
        int wid = tid >> 6, lane = tid & 63;
        if (lane == 0) ps[wid] = t;
        __syncthreads();
        if (tid == 0) out[(size_t)(b * PRED + p) * NN + n] = ps[0] + ps[1] + ps[2] + ps[3] + b2v;
        __syncthreads();
    }
}

// ---------------------------------------------------------------- launch
extern "C" void kernel_launch(void* const* d_in, const int* in_sizes, int n_in,
                              void* d_out, int out_size, void* d_ws, size_t ws_size,
                              hipStream_t stream) {
    const float* inp   = (const float*)d_in[0];
    const float* W_in  = (const float*)d_in[1];
    const float* b_in  = (const float*)d_in[2];
    const float* gcn_W = (const float*)d_in[3];
    const float* gcn_b = (const float*)d_in[4];
    const float* W1    = (const float*)d_in[5];
    const float* b1    = (const float*)d_in[6];
    const float* W2    = (const float*)d_in[7];
    const float* b2    = (const float*)d_in[8];
    const float* ew    = (const float*)d_in[9];
    const int*   src   = (const int*)d_in[10];
    const int*   dst   = (const int*)d_in[11];
    float* out = (float*)d_out;

    char* w = (char*)d_ws;
    auto alloc = [&](size_t bytes) {
        char* p = w;
        w += (bytes + 255) & ~(size_t)255;
        return p;
    };
    short* hA    = (short*)alloc((size_t)2 * ROWS_BAND * HID * 2);  // compact [X|Y]
    short* hB    = (short*)alloc((size_t)2 * ROWS_BAND * HID * 2);
    short* hl0   = (short*)alloc(BAND * 2);
    short* hl1   = (short*)alloc(BAND * 2);
    short* xproj = (short*)alloc((size_t)13 * BAND * 2);
    short* Wt    = (short*)alloc((size_t)3 * 65536 * 2);
    float* inv_in  = (float*)alloc(400 * 4);
    float* csum    = (float*)alloc(400 * 4);
    int*   csr_off = (int*)alloc(401 * 4);
    int*   csr_srcv= (int*)alloc(CSR_CAP * 4);
    float* cf1     = (float*)alloc(CSR_CAP * 4);
    float* cf2     = (float*)alloc(CSR_CAP * 4);
    float* stats   = (float*)alloc(12 * 4);

    k_graph<<<49, 256, 0, stream>>>(src, dst, ew, gcn_W, inv_in, csum, csr_off,
                                    csr_srcv, cf1, cf2, Wt, stats);
    k_xproj<<<5200, 256, 0, stream>>>(inp, W_in, b_in, gcn_b + 512, xproj, stats);

    short* hlbuf[2] = {hl0, hl1};
    const int lefts[4] = {0, 4, 7, 10};
    const size_t RB = (size_t)ROWS_BAND * HID;
    for (int it = 0; it < 4; ++it) {
        int t1 = (it == 0) ? 1 : lefts[it];
        int t3 = (it == 0) ? 3 : lefts[it] + 2;
        const short* hlp = (it == 0) ? xproj : hlbuf[(it - 1) & 1];
        const float* stA = (it == 0) ? stats + 8 : stats + (it - 1) * 2;
        short* cur = hlbuf[it & 1];
        k_layer<0><<<200, 256, 0, stream>>>(hlp, xproj + (size_t)t3 * BAND, stA, csum,
                                            inv_in, csr_off, csr_srcv, cf1, cf2,
                                            Wt, gcn_b,
                                            nullptr, nullptr, nullptr, nullptr,
                                            hA, nullptr);
        k_layer<1><<<200, 256, 0, stream>>>(hA, hA + RB, stats + 8, csum,
                                            inv_in, csr_off, csr_srcv, cf1, cf2,
                                            Wt + 65536, gcn_b + 256,
                                            nullptr, nullptr, nullptr, nullptr,
                                            hB, nullptr);
        k_layer<2><<<200, 256, 0, stream>>>(hB, hB + RB, stats + 8, csum,
                                            inv_in, csr_off, csr_srcv, cf1, cf2,
                                            Wt + 131072, gcn_b + 512,
                                            hlp, stA, xproj + (size_t)t1 * BAND,
                                            xproj + (size_t)t3 * BAND,
                                            cur, stats + it * 2);
    }

    k_head<<<dim3(NN, BB), 256, 0, stream>>>(hlbuf[1], stats + 6, W1, b1, W2, b2, out);
}

// Round 7
// 287.910 us; speedup vs baseline: 4.6208x; 1.1375x over previous
//
#include <hip/hip_runtime.h>

// Problem constants (fixed by the reference)
#define BB 16
#define HIS 13
#define NN 400
#define DIN 16
#define HID 256
#define PRED 12
#define NE 9600
#define EPSF 1e-5f
#define HSZ ((size_t)25600*256)            // full h element count (LN stats denom)
#define BAND ((size_t)NN*BB*HID)           // 1,638,400 elems (one t-band)
#define ROWS_BAND (NN*BB)                  // 6400 rows per band
#define CSR_CAP 6144

typedef __attribute__((ext_vector_type(8))) short short8v;
typedef __attribute__((ext_vector_type(4))) float f32x4;

__device__ __forceinline__ short f2bf(float x) {
    unsigned u = __float_as_uint(x);
    return (short)((u + 0x7FFF + ((u >> 16) & 1)) >> 16);
}
__device__ __forceinline__ float bf2f(short x) {
    return __uint_as_float(((unsigned)(unsigned short)x) << 16);
}
__device__ __forceinline__ void gload16(const void* g, void* l) {
    __builtin_amdgcn_global_load_lds((const __attribute__((address_space(1))) void*)g,
                                     (__attribute__((address_space(3))) void*)l,
                                     16, 0, 0);
}

// ------------------------------------------------------------ fused prep
// block 0        : degrees; single padded (x8) X CSR; cf1/cf2; csum; inv_in;
//                  identity affine slot stats[9]
// blocks 1..48   : Wt[l][n][k] = bf16(gcn_W[l][k][n]) tile transpose
// blocks 49..1348: input projections, 4 jobs each (job = time*400+n).
//                  stat times {2,5,8,11} -> sum/sumsq into stats[it*2] (atomic);
//                  others -> bf16 band xproj[time][n][b][hid]
__global__ __launch_bounds__(256) void k_prep(
    const int* __restrict__ src, const int* __restrict__ dst,
    const float* __restrict__ ew, const float* __restrict__ gcn_W,
    const float* __restrict__ inp, const float* __restrict__ W_in,
    const float* __restrict__ b_in, const float* __restrict__ gb2,
    float* __restrict__ inv_in, float* __restrict__ csum,
    int* __restrict__ csr_off, int* __restrict__ csr_src,
    float* __restrict__ cf1, float* __restrict__ cf2,
    short* __restrict__ Wt, short* __restrict__ xproj,
    float* __restrict__ stats)
{
    __shared__ __align__(16) char SM[17408];
    int t = threadIdx.x, bi = blockIdx.x;
    if (bi == 0) {
        int* odeg = (int*)SM;              // 1600
        int* ideg = odeg + 1600;           // 400
        int* cnt  = ideg + 400;            // 400
        int* offl = cnt + 400;             // 401
        int* scan_t = offl + 401;          // 256
        float* csuml = (float*)(scan_t + 256); // 400
        for (int g = t; g < 1600; g += 256) odeg[g] = 0;
        for (int g = t; g < 400; g += 256) { ideg[g] = 0; cnt[g] = 0; csuml[g] = 0.f; }
        if (t == 9) stats[9] = (1.0f - EPSF) * (float)HSZ;   // identity affine slot
        __syncthreads();
        for (int e = t; e < NE; e += 256) atomicAdd(&odeg[src[e]], 1);
        for (int e = t; e < 3200; e += 256) atomicAdd(&ideg[dst[e]], 1);
        __syncthreads();
        // padded counts (x8) + parallel exclusive scan over 400
        int s = 0, p0 = 0, p1 = 0;
        if (t < 200) {
            p0 = (ideg[2 * t] + 7) & ~7;
            p1 = (ideg[2 * t + 1] + 7) & ~7;
            s = p0 + p1;
        }
        scan_t[t] = s;
        __syncthreads();
        for (int o = 1; o < 256; o <<= 1) {
            int v = (t >= o) ? scan_t[t - o] : 0;
            __syncthreads();
            scan_t[t] += v;
            __syncthreads();
        }
        if (t < 200) { int base = scan_t[t] - s; offl[2 * t] = base; offl[2 * t + 1] = base + p0; }
        if (t == 255) offl[400] = scan_t[255];
        __syncthreads();
        int cap = offl[400];
        for (int g = t; g < 401; g += 256) csr_off[g] = offl[g];
        for (int g = t; g < 400; g += 256) inv_in[g] = rsqrtf(fmaxf((float)ideg[g], 1.f));
        for (int i = t; i < cap; i += 256) { csr_src[i] = 0; cf1[i] = 0.f; cf2[i] = 0.f; }
        __syncthreads();
        for (int e = t; e < 3200; e += 256) {
            int d = dst[e];                 // [0,400)
            int r = src[e];
            int p = offl[d] + atomicAdd(&cnt[d], 1);
            float w = ew[e];
            float c1 = w * rsqrtf(fmaxf((float)odeg[r], 1.f));
            float c2 = w * rsqrtf(fmaxf((float)odeg[1200 + r], 1.f));
            csr_src[p] = r;
            cf1[p] = c1;
            cf2[p] = c2;
            atomicAdd(&csuml[d], c1);
        }
        __syncthreads();
        for (int g = t; g < 400; g += 256) csum[g] = csuml[g];
    } else if (bi <= 48) {
        float (*S)[65] = (float(*)[65])SM;   // 64x65 f32
        int tile = bi - 1;            // 0..47: 3 layers x 16 (4x4 of 64)
        int l = tile / 16, sub = tile % 16;
        int k0 = (sub >> 2) * 64, n0 = (sub & 3) * 64;
        int tr = t >> 6, tc = t & 63;
#pragma unroll
        for (int i = 0; i < 16; ++i) {
            int r = i * 4 + tr;
            S[r][tc] = gcn_W[(size_t)l * 65536 + (size_t)(k0 + r) * 256 + n0 + tc];
        }
        __syncthreads();
#pragma unroll
        for (int i = 0; i < 16; ++i) {
            int n = i * 4 + tr;
            Wt[(size_t)l * 65536 + (size_t)(n0 + n) * 256 + k0 + tc] = f2bf(S[tc][n]);
        }
    } else {
        // -------- input projection, scalar-broadcast x, no LDS
        float* rbuf = (float*)SM;            // 8 floats
        float wr[16];
#pragma unroll
        for (int d = 0; d < 16; ++d) wr[d] = W_in[d * 256 + t];
        float bvv = b_in[t];
        int job0 = (bi - 49) * 4;
        int time = job0 / 400;
        int n0 = job0 % 400;
        bool isStat = (time == 2 || time == 5 || time == 8 || time == 11);
        float gb = isStat ? gb2[t] : 0.f;
        float s1 = 0.f, s2 = 0.f;
        for (int j = 0; j < 4; ++j) {
            int n = n0 + j;
            float acc[16];
#pragma unroll
            for (int b = 0; b < 16; ++b) acc[b] = bvv;
#pragma unroll
            for (int b = 0; b < 16; ++b) {
                const float* xr = inp + (((size_t)b * HIS + time) * NN + n) * DIN;
#pragma unroll
                for (int d = 0; d < 16; ++d) acc[b] = fmaf(xr[d], wr[d], acc[b]);
            }
            if (isStat) {
#pragma unroll
                for (int b = 0; b < 16; ++b) {
                    float v = acc[b] + gb;
                    s1 += v; s2 += v * v;
                }
            } else {
                size_t gbase = (size_t)time * BAND + ((size_t)n * 16) * 256 + t;
#pragma unroll
                for (int b = 0; b < 16; ++b) xproj[gbase + (size_t)b * 256] = f2bf(acc[b]);
            }
        }
        if (isStat) {
#pragma unroll
            for (int o = 32; o > 0; o >>= 1) {
                s1 += __shfl_down(s1, o, 64);
                s2 += __shfl_down(s2, o, 64);
            }
            int wid = t >> 6, lane = t & 63;
            if (lane == 0) { rbuf[wid] = s1; rbuf[4 + wid] = s2; }
            __syncthreads();
            if (t == 0) {
                int it = (time - 2) / 3;
                atomicAdd(&stats[it * 2],     rbuf[0] + rbuf[1] + rbuf[2] + rbuf[3]);
                atomicAdd(&stats[it * 2 + 1], rbuf[4] + rbuf[5] + rbuf[6] + rbuf[7]);
            }
        }
    }
}

// ------------------------------------------------------------ fused agg + MFMA GEMM
// 400 blocks: blk<200 -> X (gl = blk*2), else Y (gl = (blk-200)*2). Local rows
// [0,6400) per band; C compact = [X band | Y band].
// MODE 0: gather hX with affine(stA)+csum (X) / hY raw (Y); relu -> C.
// MODE 1: gather compact h; relu -> C.
// MODE 2: gather compact h; epilogue: X: stats with residuals affine(resX0)+resX1;
//         Y: stats + resY, write hlast band (C).
template <int MODE>
__global__ __launch_bounds__(256) void k_layer(
    const short* __restrict__ hX, const short* __restrict__ hY,
    const float* __restrict__ stA, const float* __restrict__ csum,
    const float* __restrict__ inv_in, const int* __restrict__ csr_off,
    const int* __restrict__ csr_src, const float* __restrict__ cf1,
    const float* __restrict__ cf2,
    const short* __restrict__ Bt, const float* __restrict__ bias,
    const short* __restrict__ resX0, const float* __restrict__ stR,
    const short* __restrict__ resX1, const short* __restrict__ resY,
    short* __restrict__ C, float* __restrict__ stats)
{
    __shared__ short As[32][264];
    __shared__ short Bs[2][8192];
    __shared__ float red[512];
    int tid = threadIdx.x;
    int wid = tid >> 6, l = tid & 63;
    int l15 = l & 15, l4 = l >> 4;
    int blk = blockIdx.x;
    int isY = blk >= 200;
    int gl = (isY ? blk - 200 : blk) * 2;
    int rowL0 = gl * 16;
    int wn = wid * 64;
    const short* hsrc = isY ? hY : hX;
    const float* cf = isY ? cf2 : cf1;

    // affine for MODE0 X gather
    float am = 1.f, moff = 0.f;
    if (MODE == 0 && !isY) {
        float mean = stA[0] * (1.f / (float)HSZ);
        float var  = stA[1] * (1.f / (float)HSZ) - mean * mean;
        float istd = rsqrtf(var + EPSF);
        am = istd; moff = mean * istd;
    }

    // B staging lane constants (16B-unit XOR source swizzle) + chunk-0 prefetch
    int br = l >> 2;
    int kd = (l & 3) ^ ((br >> 1) & 3);
    for (int ch = wid; ch < 16; ch += 4)
        gload16(Bt + ((size_t)(ch * 16 + br)) * 256 + kd * 8, &Bs[0][ch * 512]);

    // ---- gather: 2 g's, padded 8-edge chunks
    {
        int b = tid >> 4, hsc = (tid & 15) * 16;
        const size_t lane_off = (size_t)b * HID + hsc;
        for (int gi = 0; gi < 2; ++gi) {
            int g = gl + gi;
            int beg = csr_off[g], end = csr_off[g + 1];
            float acc[16];
#pragma unroll
            for (int i = 0; i < 16; ++i) acc[i] = 0.f;
            for (int j = beg; j < end; j += 8) {
                int ss[8]; float cc[8];
#pragma unroll
                for (int u = 0; u < 8; ++u) { ss[u] = csr_src[j + u]; cc[u] = cf[j + u]; }
                short8v va[8], vb[8];
#pragma unroll
                for (int u = 0; u < 8; ++u) {
                    const short8v* q = (const short8v*)&hsrc[(size_t)ss[u] * 4096 + lane_off];
                    va[u] = q[0]; vb[u] = q[1];
                }
#pragma unroll
                for (int u = 0; u < 8; ++u) {
#pragma unroll
                    for (int i = 0; i < 8; ++i) {
                        acc[i]     = fmaf(cc[u], bf2f(va[u][i]), acc[i]);
                        acc[8 + i] = fmaf(cc[u], bf2f(vb[u][i]), acc[8 + i]);
                    }
                }
            }
            float s = inv_in[g];
            float addv = (MODE == 0 && !isY) ? (-moff * csum[g]) : 0.f;
            short8v o0, o1;
#pragma unroll
            for (int i = 0; i < 8; ++i) o0[i] = f2bf(s * fmaf(am, acc[i], addv));
#pragma unroll
            for (int i = 0; i < 8; ++i) o1[i] = f2bf(s * fmaf(am, acc[8 + i], addv));
            int row = gi * 16 + b;
            *(short8v*)&As[row][hsc]     = o0;
            *(short8v*)&As[row][hsc + 8] = o1;
        }
    }
    __syncthreads();

    // ---- MFMA loop
    f32x4 cacc[2][4] = {};
    int xsw = (l4 ^ ((l15 >> 1) & 3)) * 8;
    for (int kc = 0; kc < 8; ++kc) {
        int cur = kc & 1;
        if (kc < 7) {
            int k0n = (kc + 1) * 32;
            for (int ch = wid; ch < 16; ch += 4)
                gload16(Bt + ((size_t)(ch * 16 + br)) * 256 + k0n + kd * 8,
                        &Bs[cur ^ 1][ch * 512]);
        }
        int k0 = kc * 32;
        short8v av[2], bv[4];
#pragma unroll
        for (int mi = 0; mi < 2; ++mi)
            av[mi] = *(const short8v*)&As[mi * 16 + l15][k0 + l4 * 8];
#pragma unroll
        for (int ni = 0; ni < 4; ++ni)
            bv[ni] = *(const short8v*)&Bs[cur][(wn + ni * 16 + l15) * 32 + xsw];
#pragma unroll
        for (int mi = 0; mi < 2; ++mi)
#pragma unroll
            for (int ni = 0; ni < 4; ++ni)
                cacc[mi][ni] = __builtin_amdgcn_mfma_f32_16x16x32_bf16(
                    av[mi], bv[ni], cacc[mi][ni], 0, 0, 0);
        __syncthreads();
    }

    // ---- epilogue
    if (MODE <= 1) {
#pragma unroll
        for (int ni = 0; ni < 4; ++ni) {
            int col = wn + ni * 16 + l15;
            float bvv = bias[col];
#pragma unroll
            for (int mi = 0; mi < 2; ++mi) {
#pragma unroll
                for (int r = 0; r < 4; ++r) {
                    float v = fmaxf(cacc[mi][ni][r] + bvv, 0.f);
                    As[mi * 16 + l4 * 4 + r][col] = f2bf(v);
                }
            }
        }
        __syncthreads();
        int row = tid >> 3, cs = (tid & 7) * 32;
        size_t gb = ((size_t)(isY ? ROWS_BAND : 0) + rowL0 + row) * HID + cs;
#pragma unroll
        for (int i = 0; i < 4; ++i)
            *(short8v*)&C[gb + i * 8] = *(const short8v*)&As[row][cs + i * 8];
    } else {
        float s1 = 0.f, s2 = 0.f;
        if (!isY) {
            float meanR = stR[0] * (1.f / (float)HSZ);
            float varR  = stR[1] * (1.f / (float)HSZ) - meanR * meanR;
            float istdR = rsqrtf(varR + EPSF);
#pragma unroll
            for (int ni = 0; ni < 4; ++ni) {
                int col = wn + ni * 16 + l15;
                float bvv = bias[col];
#pragma unroll
                for (int mi = 0; mi < 2; ++mi) {
#pragma unroll
                    for (int r = 0; r < 4; ++r) {
                        int rowg = rowL0 + mi * 16 + l4 * 4 + r;
                        size_t ix = (size_t)rowg * HID + col;
                        float base = cacc[mi][ni][r] + bvv;
                        float v1 = base + (bf2f(resX0[ix]) - meanR) * istdR;
                        float v2 = base + bf2f(resX1[ix]);
                        s1 += v1 + v2;
                        s2 += v1 * v1 + v2 * v2;
                    }
                }
            }
        } else {
#pragma unroll
            for (int ni = 0; ni < 4; ++ni) {
                int col = wn + ni * 16 + l15;
                float bvv = bias[col];
#pragma unroll
                for (int mi = 0; mi < 2; ++mi) {
#pragma unroll
                    for (int r = 0; r < 4; ++r) {
                        int rowl = mi * 16 + l4 * 4 + r;
                        size_t ix = (size_t)(rowL0 + rowl) * HID + col;
                        float v = cacc[mi][ni][r] + bvv + bf2f(resY[ix]);
                        s1 += v; s2 += v * v;
                        As[rowl][col] = f2bf(v);
                    }
                }
            }
            __syncthreads();
            int row = tid >> 3, cs = (tid & 7) * 32;
            size_t gb = (size_t)(rowL0 + row) * HID + cs;
#pragma unroll
            for (int i = 0; i < 4; ++i)
                *(short8v*)&C[gb + i * 8] = *(const short8v*)&As[row][cs + i * 8];
        }
        red[tid] = s1; red[256 + tid] = s2;
        __syncthreads();
        for (int o = 128; o > 0; o >>= 1) {
            if (tid < o) { red[tid] += red[tid + o]; red[256 + tid] += red[256 + tid + o]; }
            __syncthreads();
        }
        if (tid == 0) { atomicAdd(&stats[0], red[0]); atomicAdd(&stats[1], red[256]); }
    }
}

// ---------------------------------------------------------------- head
__global__ void k_head(const short* __restrict__ hlast, const float* __restrict__ st,
                       const float* __restrict__ W1, const float* __restrict__ b1,
                       const float* __restrict__ W2, const float* __restrict__ b2,
                       float* __restrict__ out) {
    float mean = st[0] * (1.0f / (float)HSZ);
    float var  = st[1] * (1.0f / (float)HSZ) - mean * mean;
    float istd = rsqrtf(var + EPSF);
    int n = blockIdx.x, b = blockIdx.y, tid = threadIdx.x;
    float v  = (bf2f(hlast[((size_t)n * BB + b) * HID + tid]) - mean) * istd;
    float w2 = W2[tid];
    float b2v = b2[0];
    __shared__ float ps[4];
    for (int p = 0; p < PRED; ++p) {
        float t = fmaxf(fmaf(v, W1[p], b1[p]), 0.f) * w2;
#pragma unroll
        for (int o = 32; o > 0; o >>= 1) t += __shfl_down(t, o, 64);
        int wid = tid >> 6, lane = tid & 63;
        if (lane == 0) ps[wid] = t;
        __syncthreads();
        if (tid == 0) out[(size_t)(b * PRED + p) * NN + n] = ps[0] + ps[1] + ps[2] + ps[3] + b2v;
        __syncthreads();
    }
}

// ---------------------------------------------------------------- launch
extern "C" void kernel_launch(void* const* d_in, const int* in_sizes, int n_in,
                              void* d_out, int out_size, void* d_ws, size_t ws_size,
                              hipStream_t stream) {
    const float* inp   = (const float*)d_in[0];
    const float* W_in  = (const float*)d_in[1];
    const float* b_in  = (const float*)d_in[2];
    const float* gcn_W = (const float*)d_in[3];
    const float* gcn_b = (const float*)d_in[4];
    const float* W1    = (const float*)d_in[5];
    const float* b1    = (const float*)d_in[6];
    const float* W2    = (const float*)d_in[7];
    const float* b2    = (const float*)d_in[8];
    const float* ew    = (const float*)d_in[9];
    const int*   src   = (const int*)d_in[10];
    const int*   dst   = (const int*)d_in[11];
    float* out = (float*)d_out;

    char* w = (char*)d_ws;
    auto alloc = [&](size_t bytes) {
        char* p = w;
        w += (bytes + 255) & ~(size_t)255;
        return p;
    };
    short* hA    = (short*)alloc((size_t)2 * ROWS_BAND * HID * 2);  // compact [X|Y]
    short* hB    = (short*)alloc((size_t)2 * ROWS_BAND * HID * 2);
    short* hl0   = (short*)alloc(BAND * 2);
    short* hl1   = (short*)alloc(BAND * 2);
    short* xproj = (short*)alloc((size_t)13 * BAND * 2);
    short* Wt    = (short*)alloc((size_t)3 * 65536 * 2);
    float* inv_in  = (float*)alloc(400 * 4);
    float* csum    = (float*)alloc(400 * 4);
    int*   csr_off = (int*)alloc(401 * 4);
    int*   csr_srcv= (int*)alloc(CSR_CAP * 4);
    float* cf1     = (float*)alloc(CSR_CAP * 4);
    float* cf2     = (float*)alloc(CSR_CAP * 4);
    float* stats   = (float*)alloc(12 * 4);

    hipMemsetAsync(stats, 0, 12 * 4, stream);
    k_prep<<<1349, 256, 0, stream>>>(src, dst, ew, gcn_W, inp, W_in, b_in,
                                     gcn_b + 512, inv_in, csum, csr_off,
                                     csr_srcv, cf1, cf2, Wt, xproj, stats);

    short* hlbuf[2] = {hl0, hl1};
    const int lefts[4] = {0, 4, 7, 10};
    const size_t RB = (size_t)ROWS_BAND * HID;
    for (int it = 0; it < 4; ++it) {
        int t1 = (it == 0) ? 1 : lefts[it];
        int t3 = (it == 0) ? 3 : lefts[it] + 2;
        const short* hlp = (it == 0) ? xproj : hlbuf[(it - 1) & 1];
        const float* stA = (it == 0) ? stats + 8 : stats + (it - 1) * 2;
        short* cur = hlbuf[it & 1];
        k_layer<0><<<400, 256, 0, stream>>>(hlp, xproj + (size_t)t3 * BAND, stA, csum,
                                            inv_in, csr_off, csr_srcv, cf1, cf2,
                                            Wt, gcn_b,
                                            nullptr, nullptr, nullptr, nullptr,
                                            hA, nullptr);
        k_layer<1><<<400, 256, 0, stream>>>(hA, hA + RB, stats + 8, csum,
                                            inv_in, csr_off, csr_srcv, cf1, cf2,
                                            Wt + 65536, gcn_b + 256,
                                            nullptr, nullptr, nullptr, nullptr,
                                            hB, nullptr);
        k_layer<2><<<400, 256, 0, stream>>>(hB, hB + RB, stats + 8, csum,
                                            inv_in, csr_off, csr_srcv, cf1, cf2,
                                            Wt + 131072, gcn_b + 512,
                                            hlp, stA, xproj + (size_t)t1 * BAND,
                                            xproj + (size_t)t3 * BAND,
                                            cur, stats + it * 2);
    }

    k_head<<<dim3(NN, BB), 256, 0, stream>>>(hlbuf[1], stats + 6, W1, b1, W2, b2, out);
}